// Round 11
// baseline (614.992 us; speedup 1.0000x reference)
//
#include <hip/hip_runtime.h>
#include <hip/hip_bf16.h>

namespace {

constexpr int NN = 50000;
constexpr int NE = 800000;

typedef __attribute__((ext_vector_type(8))) short bf16x8;
typedef __attribute__((ext_vector_type(4))) float f32x4;

__device__ __forceinline__ short f2bf(float f) {
  union { __hip_bfloat16 h; short s; } u;
  u.h = __float2bfloat16(f);
  return u.s;
}
__device__ __forceinline__ float bf2f(short s) {
  union { unsigned int u; float f; } v;
  v.u = ((unsigned int)(unsigned short)s) << 16;
  return v.f;
}
__device__ __forceinline__ unsigned int pkbf2(float a, float b) {
  return (unsigned int)(unsigned short)f2bf(a) |
         ((unsigned int)(unsigned short)f2bf(b) << 16);
}

// ---------- weight repack (all 14 in one launch) ----------
struct WTab {
  const float* W[14];
  short* out[14];
  int din[14];
  int dout[14];
};

__global__ __launch_bounds__(256) void wfrag_all(WTab tab) {
  int wi = blockIdx.y;
  int din = tab.din[wi], dout = tab.dout[wi];
  int total = din * dout;
  int gid = blockIdx.x * 256 + threadIdx.x;
  if (gid >= total) return;
  const float* W = tab.W[wi];
  short* Wf = tab.out[wi];
  int j = gid & 7;
  int l = (gid >> 3) & 63;
  int rest = gid >> 9;
  int nK = din >> 5;
  int kc = rest % nK;
  int t = rest / nK;
  int n = t * 16 + (l & 15);
  int k = kc * 32 + (l >> 4) * 8 + j;
  Wf[gid] = f2bf(W[(size_t)k * dout + n]);
}

// ---------- CSR build ----------
__global__ __launch_bounds__(256) void hist_kernel(const int* __restrict__ edst,
                                                   int* __restrict__ deg) {
  int e = blockIdx.x * 256 + threadIdx.x;
  if (e < NE) atomicAdd(&deg[edst[e]], 1);
}

__global__ __launch_bounds__(256) void scan1_kernel(const int* __restrict__ deg,
                                                    int* __restrict__ excl,
                                                    int* __restrict__ bsum, int N) {
  __shared__ int s[256];
  int tid = threadIdx.x;
  int i = blockIdx.x * 256 + tid;
  int v = (i < N) ? deg[i] : 0;
  s[tid] = v;
  __syncthreads();
  for (int d = 1; d < 256; d <<= 1) {
    int t = (tid >= d) ? s[tid - d] : 0;
    __syncthreads();
    s[tid] += t;
    __syncthreads();
  }
  if (i < N) excl[i] = s[tid] - v;
  if (tid == 255) bsum[blockIdx.x] = s[255];
}

__global__ __launch_bounds__(256) void scan2_kernel(const int* __restrict__ bsum,
                                                    int* __restrict__ boff, int nb) {
  __shared__ int s[256];
  int tid = threadIdx.x;
  int v = (tid < nb) ? bsum[tid] : 0;
  s[tid] = v;
  __syncthreads();
  for (int d = 1; d < 256; d <<= 1) {
    int t = (tid >= d) ? s[tid - d] : 0;
    __syncthreads();
    s[tid] += t;
    __syncthreads();
  }
  if (tid <= nb) boff[tid] = s[tid] - v;
}

__global__ __launch_bounds__(256) void scan3_kernel(const int* __restrict__ excl,
                                                    const int* __restrict__ boff,
                                                    int* __restrict__ row_start,
                                                    int N, int nb) {
  int i = blockIdx.x * 256 + threadIdx.x;
  if (i < N) row_start[i] = excl[i] + boff[i >> 8];
  else if (i == N) row_start[N] = boff[nb];
}

// fill: CSR slot pos gets {src, dst, eid} in csrMeta[pos], [NE+pos], [2NE+pos]
__global__ __launch_bounds__(256) void fill_kernel(const int* __restrict__ esrc,
                                                   const int* __restrict__ edst,
                                                   const int* __restrict__ row_start,
                                                   int* __restrict__ cursor,
                                                   int* __restrict__ csrMeta) {
  int e = blockIdx.x * 256 + threadIdx.x;
  if (e >= NE) return;
  int d = edst[e];
  int p = atomicAdd(&cursor[d], 1);
  int pos = row_start[d] + p;
  csrMeta[pos] = esrc[e];
  csrMeta[NE + pos] = d;
  csrMeta[2 * NE + pos] = e;
}

// ---------- segment-sum: 4 nodes/wave, 16 lanes per node ----------
__global__ __launch_bounds__(256) void agg_kernel(const ushort* __restrict__ yb,
                                                  const int* __restrict__ row_start,
                                                  const int* __restrict__ adj,
                                                  ushort* __restrict__ aggb) {
  int gid = blockIdx.x * 256 + threadIdx.x;
  int lane = gid & 63;
  int g = lane >> 4;
  int q = lane & 15;
  int n = (gid >> 6) * 4 + g;
  int s0 = row_start[n], s1 = row_start[n + 1];
  float a0 = 0, a1 = 0, a2 = 0, a3 = 0, a4 = 0, a5 = 0, a6 = 0, a7 = 0;
  int nfull = s0 + ((s1 - s0) & ~15);
  int base = s0;
  for (; base < nfull; base += 16) {
    int idx = adj[base + q];
#pragma unroll
    for (int j = 0; j < 16; ++j) {
      int s = __shfl(idx, g * 16 + j);
      uint4 v = *reinterpret_cast<const uint4*>(yb + (size_t)s * 128 + q * 8);
      a0 += bf2f((short)(v.x & 0xffff)); a1 += bf2f((short)(v.x >> 16));
      a2 += bf2f((short)(v.y & 0xffff)); a3 += bf2f((short)(v.y >> 16));
      a4 += bf2f((short)(v.z & 0xffff)); a5 += bf2f((short)(v.z >> 16));
      a6 += bf2f((short)(v.w & 0xffff)); a7 += bf2f((short)(v.w >> 16));
    }
  }
  if (base < s1) {
    int idx = 0;
    if (base + q < s1) idx = adj[base + q];
    int cnt = s1 - base;
#pragma unroll
    for (int j = 0; j < 16; ++j) {
      if (j < cnt) {
        int s = __shfl(idx, g * 16 + j);
        uint4 v = *reinterpret_cast<const uint4*>(yb + (size_t)s * 128 + q * 8);
        a0 += bf2f((short)(v.x & 0xffff)); a1 += bf2f((short)(v.x >> 16));
        a2 += bf2f((short)(v.y & 0xffff)); a3 += bf2f((short)(v.y >> 16));
        a4 += bf2f((short)(v.z & 0xffff)); a5 += bf2f((short)(v.z >> 16));
        a6 += bf2f((short)(v.w & 0xffff)); a7 += bf2f((short)(v.w >> 16));
      }
    }
  }
  uint4 o;
  o.x = pkbf2(a0, a1);
  o.y = pkbf2(a2, a3);
  o.z = pkbf2(a4, a5);
  o.w = pkbf2(a6, a7);
  *reinterpret_cast<uint4*>(aggb + (size_t)n * 128 + q * 8) = o;
}

// ---------- MFMA helpers ----------
// A tile: [rows][128 bf16 cols], row stride 256B, XOR swizzle ((row&7)<<4).
// B weights LDS layout == global fragment layout: granule (t*NKC+kc)*64+lane.

template <int NG, int NTHR>
__device__ __forceinline__ void wcopy(short* dst, const short* __restrict__ src,
                                      int tid) {
#pragma unroll
  for (int g0 = 0; g0 < NG; g0 += NTHR) {
    int g = g0 + tid;
    if (g < NG)
      *reinterpret_cast<bf16x8*>(dst + (size_t)g * 8) =
          *reinterpret_cast<const bf16x8*>(src + (size_t)g * 8);
  }
}

// NM=1 GEMM: one 16-row m-tile per wave, B from LDS; setprio around MFMA (T5).
template <int KCPH, int NT>
__device__ __forceinline__ void gemm16(const char* tb, const short* wbuf,
                                       int rbase, int lane, f32x4 (&acc)[NT]) {
#pragma unroll
  for (int kc = 0; kc < KCPH; ++kc) {
    int row = rbase + (lane & 15);
    int off = (row * 256 + kc * 64 + (lane >> 4) * 16) ^ ((row & 7) << 4);
    bf16x8 a = *reinterpret_cast<const bf16x8*>(tb + off);
    __builtin_amdgcn_s_setprio(1);
#pragma unroll
    for (int t = 0; t < NT; ++t) {
      bf16x8 b = *reinterpret_cast<const bf16x8*>(wbuf + ((size_t)((t * KCPH + kc) * 64 + lane)) * 8);
      acc[t] = __builtin_amdgcn_mfma_f32_16x16x32_bf16(a, b, acc[t], 0, 0, 0);
    }
    __builtin_amdgcn_s_setprio(0);
  }
}

template <int NT>
__device__ __forceinline__ void zero16(f32x4 (&acc)[NT]) {
  const f32x4 vzero = {0.f, 0.f, 0.f, 0.f};
#pragma unroll
  for (int t = 0; t < NT; ++t) acc[t] = vzero;
}

template <int NT, bool RELU>
__device__ __forceinline__ void epi16(char* dst, int rbase, int lane,
                                      const float* bias, f32x4 (&acc)[NT]) {
#pragma unroll
  for (int t = 0; t < NT; ++t) {
    int col = t * 16 + (lane & 15);
    float bb = bias[col];
#pragma unroll
    for (int i = 0; i < 4; ++i) {
      int row = rbase + (lane >> 4) * 4 + i;
      float h = acc[t][i] + bb;
      if (RELU) h = fmaxf(h, 0.f);
      int off = (row * 256 + col * 2) ^ ((row & 7) << 4);
      *reinterpret_cast<short*>(dst + off) = f2bf(h);
    }
  }
}

// ---------- node MLP f/g: 1024 thr, 16 waves x 16 rows, weights LDS-resident ----------
template <bool INBF16, bool SKIP, bool WY>
__global__ __launch_bounds__(1024, 1) void mlp_big(
    const void* __restrict__ Xv,
    const short* __restrict__ W1f, const float* __restrict__ b1,
    const short* __restrict__ W2f, const float* __restrict__ b2,
    float* __restrict__ y, ushort* __restrict__ bfout, int nrows) {
  __shared__ alignas(16) short tile_[256 * 128];  // 64 KB
  __shared__ alignas(16) short wb1[16384];        // 32 KB
  __shared__ alignas(16) short wb2[16384];        // 32 KB
  char* tb = reinterpret_cast<char*>(tile_);
  const int tid = threadIdx.x;
  const int lane = tid & 63;
  const int wave = tid >> 6;  // 0..15
  const int row0 = blockIdx.x * 256;
  const int wbase = wave * 16;

  wcopy<2048, 1024>(wb1, W1f, tid);
  wcopy<2048, 1024>(wb2, W2f, tid);
  __syncthreads();  // the only block barrier

  if constexpr (INBF16) {
    const ushort* X = (const ushort*)Xv;
#pragma unroll
    for (int it = 0; it < 4; ++it) {
      int idx = it * 64 + lane;
      int r = wbase + (idx >> 4);
      int c = idx & 15;
      int gr = row0 + r;
      bf16x8 v = {};
      if (gr < nrows) v = *reinterpret_cast<const bf16x8*>(X + (size_t)gr * 128 + c * 8);
      int off = (r * 256 + c * 16) ^ ((r & 7) << 4);
      *reinterpret_cast<bf16x8*>(tb + off) = v;
    }
  } else {
    const float* X = (const float*)Xv;
#pragma unroll
    for (int it = 0; it < 8; ++it) {
      int idx = it * 64 + lane;
      int r = wbase + (idx >> 5);
      int c = idx & 31;
      int gr = row0 + r;
      float4 v = make_float4(0.f, 0.f, 0.f, 0.f);
      if (gr < nrows) v = *reinterpret_cast<const float4*>(X + (size_t)gr * 128 + c * 4);
      short4 p;
      p.x = f2bf(v.x); p.y = f2bf(v.y); p.z = f2bf(v.z); p.w = f2bf(v.w);
      int off = (r * 256 + c * 8) ^ ((r & 7) << 4);
      *reinterpret_cast<short4*>(tb + off) = p;
    }
  }

  // GEMM1 (K=128) -> relu -> in place
  f32x4 acc[8];
  zero16(acc);
  gemm16<4, 8>(tb, wb1, wbase, lane, acc);
  epi16<8, true>(tb, wbase, lane, b1, acc);

  // GEMM2
  f32x4 acc2[8];
  zero16(acc2);
  gemm16<4, 8>(tb, wb2, wbase, lane, acc2);

#pragma unroll
  for (int t = 0; t < 8; ++t) {
    int col = t * 16 + (lane & 15);
    float bb = b2[col];
#pragma unroll
    for (int i = 0; i < 4; ++i) {
      int row = wbase + (lane >> 4) * 4 + i;
      int gr = row0 + row;
      if (gr < nrows) {
        float v = acc2[t][i] + bb;
        if constexpr (SKIP) v += y[(size_t)gr * 128 + col];
        if constexpr (WY) y[(size_t)gr * 128 + col] = v;
        int off = (row * 256 + col * 2) ^ ((row & 7) << 4);
        *reinterpret_cast<short*>(tb + off) = f2bf(v);
      }
    }
  }
#pragma unroll
  for (int rr = 0; rr < 16; ++rr) {
    int row = wbase + rr;
    int gr = row0 + row;
    if (gr < nrows) {
      int off = (row * 256 + lane * 4) ^ ((row & 7) << 4);
      unsigned int v = *reinterpret_cast<const unsigned int*>(tb + off);
      *reinterpret_cast<unsigned int*>(bfout + (size_t)gr * 128 + lane * 2) = v;
    }
  }
}

// ---------- merged tail: gridDim.y selects k1 / k2 / h ----------
__global__ __launch_bounds__(1024, 1) void mlp_tail3(
    const ushort* __restrict__ X,
    const short* __restrict__ k1W1f, const float* __restrict__ k1b1,
    const short* __restrict__ k1W2f, const float* __restrict__ k1b2,
    const short* __restrict__ k2W1f, const float* __restrict__ k2b1,
    const short* __restrict__ k2W2f, const float* __restrict__ k2b2,
    const short* __restrict__ hW1f, const float* __restrict__ hb1,
    const short* __restrict__ hW2f, const float* __restrict__ hb2,
    ushort* __restrict__ u1b, ushort* __restrict__ u2b,
    float* __restrict__ node_out, int nrows) {
  __shared__ alignas(16) short tile_[256 * 128];  // 64 KB
  __shared__ alignas(16) short wb1[16384];        // 32 KB
  __shared__ alignas(16) short wb2[16384];        // 32 KB
  char* tb = reinterpret_cast<char*>(tile_);
  const int tid = threadIdx.x;
  const int lane = tid & 63;
  const int wave = tid >> 6;
  const int row0 = blockIdx.x * 256;
  const int wbase = wave * 16;
  const int mode = blockIdx.y;  // 0: k1->u1b, 1: k2->u2b, 2: h->node_out

  const short* W1f = (mode == 0) ? k1W1f : (mode == 1) ? k2W1f : hW1f;
  const float* b1 = (mode == 0) ? k1b1 : (mode == 1) ? k2b1 : hb1;
  const short* W2f = (mode == 0) ? k1W2f : (mode == 1) ? k2W2f : hW2f;
  const float* b2 = (mode == 0) ? k1b2 : (mode == 1) ? k2b2 : hb2;

  wcopy<2048, 1024>(wb1, W1f, tid);
  if (mode < 2) wcopy<2048, 1024>(wb2, W2f, tid);
  else wcopy<1024, 1024>(wb2, W2f, tid);
  __syncthreads();  // the only block barrier

#pragma unroll
  for (int it = 0; it < 4; ++it) {
    int idx = it * 64 + lane;
    int r = wbase + (idx >> 4);
    int c = idx & 15;
    int gr = row0 + r;
    bf16x8 v = {};
    if (gr < nrows) v = *reinterpret_cast<const bf16x8*>(X + (size_t)gr * 128 + c * 8);
    int off = (r * 256 + c * 16) ^ ((r & 7) << 4);
    *reinterpret_cast<bf16x8*>(tb + off) = v;
  }

  f32x4 acc[8];
  zero16(acc);
  gemm16<4, 8>(tb, wb1, wbase, lane, acc);
  epi16<8, true>(tb, wbase, lane, b1, acc);

  if (mode < 2) {
    f32x4 acc2[8];
    zero16(acc2);
    gemm16<4, 8>(tb, wb2, wbase, lane, acc2);
    epi16<8, false>(tb, wbase, lane, b2, acc2);
    ushort* ub = (mode == 0) ? u1b : u2b;
#pragma unroll
    for (int rr = 0; rr < 16; ++rr) {
      int row = wbase + rr;
      int gr = row0 + row;
      if (gr < nrows) {
        int off = (row * 256 + lane * 4) ^ ((row & 7) << 4);
        unsigned int v = *reinterpret_cast<const unsigned int*>(tb + off);
        *reinterpret_cast<unsigned int*>(ub + (size_t)gr * 128 + lane * 2) = v;
      }
    }
  } else {
    f32x4 acc2[4];
    zero16(acc2);
    gemm16<4, 4>(tb, wb2, wbase, lane, acc2);
#pragma unroll
    for (int t = 0; t < 4; ++t) {
      int col = t * 16 + (lane & 15);
      float bb = b2[col];
#pragma unroll
      for (int i = 0; i < 4; ++i) {
        int row = wbase + (lane >> 4) * 4 + i;
        int gr = row0 + row;
        if (gr < nrows) node_out[(size_t)gr * 64 + col] = acc2[t][i] + bb;
      }
    }
  }
}

// ---------- edge kernel: persistent, CSR(dst-grouped) edge order ----------
// csrMeta: [pos]=src, [NE+pos]=dst, [2NE+pos]=eid. Processing in CSR order makes
// u2[dst] repeat ~deg times consecutively -> L1-hot; out/xe keyed by eid.
__device__ __forceinline__ void load_tile_regs(const float* __restrict__ xe,
                                               const int* __restrict__ csrMeta,
                                               int p0, int lane,
                                               int& meta, float4 (&xr)[4]) {
  int q = lane & 15;
  int which = lane >> 4;
  int w = (which < 3) ? which : 2;
  meta = csrMeta[(size_t)w * NE + p0 + q];  // lanes 0-15:src 16-31:dst 32-47:eid
#pragma unroll
  for (int i = 0; i < 4; ++i) {
    int idx = i * 64 + lane;
    int r = idx >> 4, c = idx & 15;
    int eid = __shfl(meta, 32 + r);
    xr[i] = *reinterpret_cast<const float4*>(xe + (size_t)eid * 64 + c * 4);
  }
}

__global__ __launch_bounds__(1024, 1) void edge_kernel(
    const float* __restrict__ xe, const int* __restrict__ csrMeta,
    const ushort* __restrict__ u1b, const ushort* __restrict__ u2b,
    const short* __restrict__ kW1f, const float* __restrict__ kb1,
    const short* __restrict__ kW2f, const float* __restrict__ kb2,
    const short* __restrict__ lW1f, const float* __restrict__ lb1,
    const short* __restrict__ lW2f, const float* __restrict__ lb2,
    float* __restrict__ out) {
  __shared__ alignas(16) short wK1[8192];        // 16 KB (K=64, N=128)
  __shared__ alignas(16) short wK2[16384];       // 32 KB
  __shared__ alignas(16) short wL1[16384];       // 32 KB
  __shared__ alignas(16) short wL2[4096];        // 8 KB  (K=128, N=32)
  __shared__ alignas(16) short tile_[256 * 128]; // 64 KB
  __shared__ float biasL[416];                   // kb1|kb2|lb1|lb2
  char* tb = reinterpret_cast<char*>(tile_);
  const int tid = threadIdx.x;
  const int lane = tid & 63;
  const int wave = tid >> 6;  // 0..15
  const int f4 = lane & 31;
  const int hs = lane >> 5;
  const int wbase = wave * 16;

  wcopy<1024, 1024>(wK1, kW1f, tid);
  wcopy<2048, 1024>(wK2, kW2f, tid);
  wcopy<2048, 1024>(wL1, lW1f, tid);
  wcopy<512, 1024>(wL2, lW2f, tid);
  if (tid < 128) biasL[tid] = kb1[tid];
  else if (tid < 256) biasL[tid] = kb2[tid - 128];
  else if (tid < 384) biasL[tid] = lb1[tid - 256];
  else if (tid < 416) biasL[tid] = lb2[tid - 384];
  __syncthreads();  // the only block barrier

  constexpr int NTILES = NE / 256;  // 3125
  int tile = blockIdx.x;
  int mnext;
  float4 xr[4];
  load_tile_regs(xe, csrMeta, tile * 256 + wbase, lane, mnext, xr);

  for (; tile < NTILES; tile += gridDim.x) {
    const int mcur = mnext;

    // write prefetched xe (bf16) into my 16 rows, cols 0..63
#pragma unroll
    for (int i = 0; i < 4; ++i) {
      int idx = i * 64 + lane;
      int r = idx >> 4, c = idx & 15;
      short4 p;
      p.x = f2bf(xr[i].x); p.y = f2bf(xr[i].y);
      p.z = f2bf(xr[i].z); p.w = f2bf(xr[i].w);
      int rr = wbase + r;
      int off = (rr * 256 + c * 8) ^ ((rr & 7) << 4);
      *reinterpret_cast<short4*>(tb + off) = p;
    }

    // gather chunk A (local rows i*2+hs, i<4)
    ushort4 ga[4], gb[4];
#pragma unroll
    for (int i = 0; i < 4; ++i) {
      int s = __shfl(mcur, i * 2 + hs);
      int d = __shfl(mcur, 16 + i * 2 + hs);
      ga[i] = *reinterpret_cast<const ushort4*>(u1b + (size_t)s * 128 + f4 * 4);
      gb[i] = *reinterpret_cast<const ushort4*>(u2b + (size_t)d * 128 + f4 * 4);
    }

    // k GEMM1 (K=64)
    f32x4 acc[8];
    zero16(acc);
    gemm16<2, 8>(tb, wK1, wbase, lane, acc);
    epi16<8, true>(tb, wbase, lane, &biasL[0], acc);

    // issue chunk B; combine chunk A
    ushort4 ga2[4], gb2[4];
#pragma unroll
    for (int i = 0; i < 4; ++i) {
      int s = __shfl(mcur, (4 + i) * 2 + hs);
      int d = __shfl(mcur, 16 + (4 + i) * 2 + hs);
      ga2[i] = *reinterpret_cast<const ushort4*>(u1b + (size_t)s * 128 + f4 * 4);
      gb2[i] = *reinterpret_cast<const ushort4*>(u2b + (size_t)d * 128 + f4 * 4);
    }
    uint2 gsum[8];
#pragma unroll
    for (int i = 0; i < 4; ++i) {
      float s0 = bf2f((short)ga[i].x) + bf2f((short)gb[i].x);
      float s1 = bf2f((short)ga[i].y) + bf2f((short)gb[i].y);
      float s2 = bf2f((short)ga[i].z) + bf2f((short)gb[i].z);
      float s3 = bf2f((short)ga[i].w) + bf2f((short)gb[i].w);
      gsum[i] = make_uint2(pkbf2(s0, s1), pkbf2(s2, s3));
    }

    // k GEMM2 (K=128)
    zero16(acc);
    gemm16<4, 8>(tb, wK2, wbase, lane, acc);
    epi16<8, false>(tb, wbase, lane, &biasL[128], acc);

#pragma unroll
    for (int i = 0; i < 4; ++i) {
      float s0 = bf2f((short)ga2[i].x) + bf2f((short)gb2[i].x);
      float s1 = bf2f((short)ga2[i].y) + bf2f((short)gb2[i].y);
      float s2 = bf2f((short)ga2[i].z) + bf2f((short)gb2[i].z);
      float s3 = bf2f((short)ga2[i].w) + bf2f((short)gb2[i].w);
      gsum[4 + i] = make_uint2(pkbf2(s0, s1), pkbf2(s2, s3));
    }

    // e_hid += u1[src] + u2[dst]  (wave-private rows)
#pragma unroll
    for (int i = 0; i < 8; ++i) {
      int r = wbase + i * 2 + hs;
      int off = (r * 256 + f4 * 8) ^ ((r & 7) << 4);
      short4 c = *reinterpret_cast<short4*>(tb + off);
      uint2 g = gsum[i];
      short4 nw;
      nw.x = f2bf(bf2f(c.x) + bf2f((short)(g.x & 0xffff)));
      nw.y = f2bf(bf2f(c.y) + bf2f((short)(g.x >> 16)));
      nw.z = f2bf(bf2f(c.z) + bf2f((short)(g.y & 0xffff)));
      nw.w = f2bf(bf2f(c.w) + bf2f((short)(g.y >> 16)));
      *reinterpret_cast<short4*>(tb + off) = nw;
    }

    // prefetch next tile's xe + metadata (hides under GEMM3/4)
    int nt2 = tile + gridDim.x;
    if (nt2 < NTILES)
      load_tile_regs(xe, csrMeta, nt2 * 256 + wbase, lane, mnext, xr);

    // l GEMM3 (K=128)
    zero16(acc);
    gemm16<4, 8>(tb, wL1, wbase, lane, acc);
    epi16<8, true>(tb, wbase, lane, &biasL[256], acc);

    // l GEMM4 (K=128, N=32)
    f32x4 acc4[2];
    zero16(acc4);
    gemm16<4, 2>(tb, wL2, wbase, lane, acc4);

    // scatter output rows by original edge id (one full 128B line per row)
#pragma unroll
    for (int t = 0; t < 2; ++t) {
      int col = t * 16 + (lane & 15);
      float bb = biasL[384 + col];
#pragma unroll
      for (int i = 0; i < 4; ++i) {
        int rowIdx = (lane >> 4) * 4 + i;
        int eid = __shfl(mcur, 32 + rowIdx);
        out[(size_t)eid * 32 + col] = acc4[t][i] + bb;
      }
    }
  }
}

}  // namespace

extern "C" void kernel_launch(void* const* d_in, const int* in_sizes, int n_in,
                              void* d_out, int out_size, void* d_ws, size_t ws_size,
                              hipStream_t stream) {
  const float* x = (const float*)d_in[0];
  const float* xe = (const float*)d_in[1];
  const int* eidx = (const int*)d_in[2];
  const int* esrc = eidx;
  const int* edst = eidx + NE;

  const float* fb1 = (const float*)d_in[4];
  const float* fb2 = (const float*)d_in[6];
  const float* gb1 = (const float*)d_in[8];
  const float* gb2 = (const float*)d_in[10];
  const float* hb1 = (const float*)d_in[12];
  const float* hb2 = (const float*)d_in[14];
  const float* k1b1 = (const float*)d_in[16];
  const float* k1b2 = (const float*)d_in[18];
  const float* k2b1 = (const float*)d_in[20];
  const float* k2b2 = (const float*)d_in[22];
  const float* kb1 = (const float*)d_in[24];
  const float* kb2 = (const float*)d_in[26];
  const float* lb1 = (const float*)d_in[28];
  const float* lb2 = (const float*)d_in[30];

  char* ws = (char*)d_ws;
  size_t off = 0;
  auto alloc = [&](size_t bytes) -> void* {
    void* p = ws + off;
    off = (off + bytes + 255) & ~(size_t)255;
    return p;
  };
  float* y = (float*)alloc((size_t)NN * 128 * 4);
  ushort* ybA = (ushort*)alloc((size_t)NN * 128 * 2);
  ushort* ybB = (ushort*)alloc((size_t)NN * 128 * 2);
  ushort* aggb = (ushort*)alloc((size_t)NN * 128 * 2);
  ushort* u1b = (ushort*)alloc((size_t)NN * 128 * 2);
  ushort* u2b = (ushort*)alloc((size_t)NN * 128 * 2);
  int* deg = (int*)alloc((size_t)NN * 4);
  int* excl = (int*)alloc((size_t)NN * 4);
  int* bsum = (int*)alloc(256 * 4);
  int* boff = (int*)alloc(256 * 4);
  int* row_start = (int*)alloc((size_t)(NN + 16) * 4);
  int* cursor = (int*)alloc((size_t)NN * 4);
  int* csrMeta = (int*)alloc((size_t)3 * NE * 4);  // [src | dst | eid]

  // weight fragment buffers (single fused repack launch)
  const int wi[14] = {3, 5, 7, 9, 11, 13, 15, 17, 19, 21, 23, 25, 27, 29};
  const int wdin[14] = {128, 128, 128, 128, 128, 128, 128, 128, 128, 128, 64, 128, 128, 128};
  const int wdout[14] = {128, 128, 128, 128, 128, 64, 128, 128, 128, 128, 128, 128, 128, 32};
  WTab tab;
  short* wf[14];
  for (int i = 0; i < 14; ++i) {
    size_t elems = (size_t)wdin[i] * wdout[i];
    wf[i] = (short*)alloc(elems * 2);
    tab.W[i] = (const float*)d_in[wi[i]];
    tab.out[i] = wf[i];
    tab.din[i] = wdin[i];
    tab.dout[i] = wdout[i];
  }
  wfrag_all<<<dim3(64, 14, 1), 256, 0, stream>>>(tab);

  short* fW1f = wf[0];  short* fW2f = wf[1];
  short* gW1f = wf[2];  short* gW2f = wf[3];
  short* hW1f = wf[4];  short* hW2f = wf[5];
  short* k1W1f = wf[6]; short* k1W2f = wf[7];
  short* k2W1f = wf[8]; short* k2W2f = wf[9];
  short* kW1f = wf[10]; short* kW2f = wf[11];
  short* lW1f = wf[12]; short* lW2f = wf[13];

  // CSR build
  const int nb = (NN + 255) / 256;  // 196
  hipMemsetAsync(deg, 0, (size_t)NN * 4, stream);
  hist_kernel<<<(NE + 255) / 256, 256, 0, stream>>>(edst, deg);
  scan1_kernel<<<nb, 256, 0, stream>>>(deg, excl, bsum, NN);
  scan2_kernel<<<1, 256, 0, stream>>>(bsum, boff, nb);
  scan3_kernel<<<(NN + 256) / 256 + 1, 256, 0, stream>>>(excl, boff, row_start, NN, nb);
  hipMemsetAsync(cursor, 0, (size_t)NN * 4, stream);
  fill_kernel<<<(NE + 255) / 256, 256, 0, stream>>>(esrc, edst, row_start, cursor, csrMeta);

  const int nblk = (NN + 255) / 256;  // 196 tiles of 256 rows

  // y = f(x): f32 y + bf16 ybA
  mlp_big<false, false, true><<<nblk, 1024, 0, stream>>>(
      x, fW1f, fb1, fW2f, fb2, y, ybA, NN);

  // 3 MP steps: agg (parallel CSR gather) then g; last step skips dead y-write
  ushort* ybin = ybA;
  ushort* ybout = ybB;
  for (int s = 0; s < 3; ++s) {
    agg_kernel<<<(NN / 4 * 64) / 256, 256, 0, stream>>>(ybin, row_start, csrMeta, aggb);
    if (s < 2)
      mlp_big<true, true, true><<<nblk, 1024, 0, stream>>>(
          aggb, gW1f, gb1, gW2f, gb2, y, ybout, NN);
    else
      mlp_big<true, true, false><<<nblk, 1024, 0, stream>>>(
          aggb, gW1f, gb1, gW2f, gb2, y, ybout, NN);
    ushort* t = ybin; ybin = ybout; ybout = t;
  }

  // u1 = k1(y), u2 = k2(y), node_out = h(y) — one merged launch, 588 blocks
  mlp_tail3<<<dim3(nblk, 3), 1024, 0, stream>>>(
      ybin, k1W1f, k1b1, k1W2f, k1b2, k2W1f, k2b1, k2W2f, k2b2,
      hW1f, hb1, hW2f, hb2, u1b, u2b, (float*)d_out, NN);

  // edge_out = l(k(xe) + u1[src] + u2[dst]) — persistent, CSR edge order
  float* edge_out = (float*)d_out + (size_t)NN * 64;
  edge_kernel<<<256, 1024, 0, stream>>>(xe, csrMeta, u1b, u2b, kW1f, kb1, kW2f, kb2,
                                        lW1f, lb1, lW2f, lb2, edge_out);
}

// Round 12
// 560.386 us; speedup vs baseline: 1.0974x; 1.0974x over previous
//
#include <hip/hip_runtime.h>
#include <hip/hip_bf16.h>

namespace {

constexpr int NN = 50000;
constexpr int NE = 800000;

typedef __attribute__((ext_vector_type(8))) short bf16x8;
typedef __attribute__((ext_vector_type(4))) float f32x4;

__device__ __forceinline__ short f2bf(float f) {
  union { __hip_bfloat16 h; short s; } u;
  u.h = __float2bfloat16(f);
  return u.s;
}
__device__ __forceinline__ float bf2f(short s) {
  union { unsigned int u; float f; } v;
  v.u = ((unsigned int)(unsigned short)s) << 16;
  return v.f;
}
__device__ __forceinline__ unsigned int pkbf2(float a, float b) {
  return (unsigned int)(unsigned short)f2bf(a) |
         ((unsigned int)(unsigned short)f2bf(b) << 16);
}

// ---------- weight repack (all 14 in one launch) ----------
struct WTab {
  const float* W[14];
  short* out[14];
  int din[14];
  int dout[14];
};

__global__ __launch_bounds__(256) void wfrag_all(WTab tab) {
  int wi = blockIdx.y;
  int din = tab.din[wi], dout = tab.dout[wi];
  int total = din * dout;
  int gid = blockIdx.x * 256 + threadIdx.x;
  if (gid >= total) return;
  const float* W = tab.W[wi];
  short* Wf = tab.out[wi];
  int j = gid & 7;
  int l = (gid >> 3) & 63;
  int rest = gid >> 9;
  int nK = din >> 5;
  int kc = rest % nK;
  int t = rest / nK;
  int n = t * 16 + (l & 15);
  int k = kc * 32 + (l >> 4) * 8 + j;
  Wf[gid] = f2bf(W[(size_t)k * dout + n]);
}

// ---------- CSR build ----------
__global__ __launch_bounds__(256) void hist_kernel(const int* __restrict__ edst,
                                                   int* __restrict__ deg) {
  int e = blockIdx.x * 256 + threadIdx.x;
  if (e < NE) atomicAdd(&deg[edst[e]], 1);
}

__global__ __launch_bounds__(256) void scan1_kernel(const int* __restrict__ deg,
                                                    int* __restrict__ excl,
                                                    int* __restrict__ bsum, int N) {
  __shared__ int s[256];
  int tid = threadIdx.x;
  int i = blockIdx.x * 256 + tid;
  int v = (i < N) ? deg[i] : 0;
  s[tid] = v;
  __syncthreads();
  for (int d = 1; d < 256; d <<= 1) {
    int t = (tid >= d) ? s[tid - d] : 0;
    __syncthreads();
    s[tid] += t;
    __syncthreads();
  }
  if (i < N) excl[i] = s[tid] - v;
  if (tid == 255) bsum[blockIdx.x] = s[255];
}

__global__ __launch_bounds__(256) void scan2_kernel(const int* __restrict__ bsum,
                                                    int* __restrict__ boff, int nb) {
  __shared__ int s[256];
  int tid = threadIdx.x;
  int v = (tid < nb) ? bsum[tid] : 0;
  s[tid] = v;
  __syncthreads();
  for (int d = 1; d < 256; d <<= 1) {
    int t = (tid >= d) ? s[tid - d] : 0;
    __syncthreads();
    s[tid] += t;
    __syncthreads();
  }
  if (tid <= nb) boff[tid] = s[tid] - v;
}

__global__ __launch_bounds__(256) void scan3_kernel(const int* __restrict__ excl,
                                                    const int* __restrict__ boff,
                                                    int* __restrict__ row_start,
                                                    int N, int nb) {
  int i = blockIdx.x * 256 + threadIdx.x;
  if (i < N) row_start[i] = excl[i] + boff[i >> 8];
  else if (i == N) row_start[N] = boff[nb];
}

__global__ __launch_bounds__(256) void fill_kernel(const int* __restrict__ esrc,
                                                   const int* __restrict__ edst,
                                                   const int* __restrict__ row_start,
                                                   int* __restrict__ cursor,
                                                   int* __restrict__ adj) {
  int e = blockIdx.x * 256 + threadIdx.x;
  if (e >= NE) return;
  int d = edst[e];
  int p = atomicAdd(&cursor[d], 1);
  adj[row_start[d] + p] = esrc[e];
}

// ---------- segment-sum: 4 nodes/wave, 16 lanes per node ----------
__global__ __launch_bounds__(256) void agg_kernel(const ushort* __restrict__ yb,
                                                  const int* __restrict__ row_start,
                                                  const int* __restrict__ adj,
                                                  ushort* __restrict__ aggb) {
  int gid = blockIdx.x * 256 + threadIdx.x;
  int lane = gid & 63;
  int g = lane >> 4;
  int q = lane & 15;
  int n = (gid >> 6) * 4 + g;
  int s0 = row_start[n], s1 = row_start[n + 1];
  float a0 = 0, a1 = 0, a2 = 0, a3 = 0, a4 = 0, a5 = 0, a6 = 0, a7 = 0;
  for (int base = s0; base < s1; base += 16) {
    int idx = 0;
    if (base + q < s1) idx = adj[base + q];
    int cnt = s1 - base;
    if (cnt > 16) cnt = 16;
#pragma unroll
    for (int j = 0; j < 16; ++j) {
      if (j < cnt) {
        int s = __shfl(idx, g * 16 + j);
        uint4 v = *reinterpret_cast<const uint4*>(yb + (size_t)s * 128 + q * 8);
        a0 += bf2f((short)(v.x & 0xffff)); a1 += bf2f((short)(v.x >> 16));
        a2 += bf2f((short)(v.y & 0xffff)); a3 += bf2f((short)(v.y >> 16));
        a4 += bf2f((short)(v.z & 0xffff)); a5 += bf2f((short)(v.z >> 16));
        a6 += bf2f((short)(v.w & 0xffff)); a7 += bf2f((short)(v.w >> 16));
      }
    }
  }
  uint4 o;
  o.x = pkbf2(a0, a1);
  o.y = pkbf2(a2, a3);
  o.z = pkbf2(a4, a5);
  o.w = pkbf2(a6, a7);
  *reinterpret_cast<uint4*>(aggb + (size_t)n * 128 + q * 8) = o;
}

// ---------- MFMA helpers ----------
// A tile: [rows][128 bf16 cols], row stride 256B, XOR swizzle ((row&7)<<4).
// B weights LDS layout == global fragment layout: granule (t*NKC+kc)*64+lane.

template <int NG, int NTHR>
__device__ __forceinline__ void wcopy(short* dst, const short* __restrict__ src,
                                      int tid) {
#pragma unroll
  for (int g0 = 0; g0 < NG; g0 += NTHR) {
    int g = g0 + tid;
    if (g < NG)
      *reinterpret_cast<bf16x8*>(dst + (size_t)g * 8) =
          *reinterpret_cast<const bf16x8*>(src + (size_t)g * 8);
  }
}

// NM=1 GEMM: one 16-row m-tile per wave, B from LDS; setprio around MFMA (T5).
template <int KCPH, int NT>
__device__ __forceinline__ void gemm16(const char* tb, const short* wbuf,
                                       int rbase, int lane, f32x4 (&acc)[NT]) {
#pragma unroll
  for (int kc = 0; kc < KCPH; ++kc) {
    int row = rbase + (lane & 15);
    int off = (row * 256 + kc * 64 + (lane >> 4) * 16) ^ ((row & 7) << 4);
    bf16x8 a = *reinterpret_cast<const bf16x8*>(tb + off);
    __builtin_amdgcn_s_setprio(1);
#pragma unroll
    for (int t = 0; t < NT; ++t) {
      bf16x8 b = *reinterpret_cast<const bf16x8*>(wbuf + ((size_t)((t * KCPH + kc) * 64 + lane)) * 8);
      acc[t] = __builtin_amdgcn_mfma_f32_16x16x32_bf16(a, b, acc[t], 0, 0, 0);
    }
    __builtin_amdgcn_s_setprio(0);
  }
}

template <int NT>
__device__ __forceinline__ void zero16(f32x4 (&acc)[NT]) {
  const f32x4 vzero = {0.f, 0.f, 0.f, 0.f};
#pragma unroll
  for (int t = 0; t < NT; ++t) acc[t] = vzero;
}

// epilogue for 16-row wave tile; bias pointer may be global or LDS
template <int NT, bool RELU>
__device__ __forceinline__ void epi16(char* dst, int rbase, int lane,
                                      const float* bias, f32x4 (&acc)[NT]) {
#pragma unroll
  for (int t = 0; t < NT; ++t) {
    int col = t * 16 + (lane & 15);
    float bb = bias[col];
#pragma unroll
    for (int i = 0; i < 4; ++i) {
      int row = rbase + (lane >> 4) * 4 + i;
      float h = acc[t][i] + bb;
      if (RELU) h = fmaxf(h, 0.f);
      int off = (row * 256 + col * 2) ^ ((row & 7) << 4);
      *reinterpret_cast<short*>(dst + off) = f2bf(h);
    }
  }
}

// deferred epilogue: +bias (+relu) -> packed bf16 regs (2 uints per t)
template <int NT, bool RELU>
__device__ __forceinline__ void pack16(int lane, const float* bias, int col0,
                                       f32x4 (&acc)[NT], uint2 (&pk)[NT]) {
#pragma unroll
  for (int t = 0; t < NT; ++t) {
    float bb = bias[col0 + t * 16 + (lane & 15)];
    float v0 = acc[t][0] + bb, v1 = acc[t][1] + bb;
    float v2 = acc[t][2] + bb, v3 = acc[t][3] + bb;
    if (RELU) {
      v0 = fmaxf(v0, 0.f); v1 = fmaxf(v1, 0.f);
      v2 = fmaxf(v2, 0.f); v3 = fmaxf(v3, 0.f);
    }
    pk[t].x = pkbf2(v0, v1);
    pk[t].y = pkbf2(v2, v3);
  }
}

// write packed regs to tile (after all in-place reads are done)
template <int NT>
__device__ __forceinline__ void write16(char* dst, int rbase, int lane, int col0,
                                        uint2 (&pk)[NT]) {
#pragma unroll
  for (int t = 0; t < NT; ++t) {
    int col = col0 + t * 16 + (lane & 15);
#pragma unroll
    for (int i = 0; i < 4; ++i) {
      int row = rbase + (lane >> 4) * 4 + i;
      unsigned int v = (i < 2) ? pk[t].x : pk[t].y;
      short s = (short)(v >> ((i & 1) * 16));
      int off = (row * 256 + col * 2) ^ ((row & 7) << 4);
      *reinterpret_cast<short*>(dst + off) = s;
    }
  }
}

// in-place GEMM (N=128) split into two N=64 halves with deferred write:
// halves both READ the full tile before anything is written back.
template <int KCPH, bool RELU>
__device__ __forceinline__ void gemm128_inplace(char* tb, const short* wbuf,
                                                int rbase, int lane,
                                                const float* bias) {
  f32x4 acc[4];
  uint2 pkA[4], pkB[4];
  zero16(acc);
  gemm16<KCPH, 4>(tb, wbuf, rbase, lane, acc);
  pack16<4, RELU>(lane, bias, 0, acc, pkA);
  zero16(acc);
  gemm16<KCPH, 4>(tb, wbuf + (size_t)4 * KCPH * 64 * 8, rbase, lane, acc);
  pack16<4, RELU>(lane, bias, 64, acc, pkB);
  write16<4>(tb, rbase, lane, 0, pkA);
  write16<4>(tb, rbase, lane, 64, pkB);
}

// ---------- node MLP f/g: 1024 thr, 16 waves x 16 rows, weights LDS-resident ----------
template <bool INBF16, bool SKIP, bool WY>
__global__ __launch_bounds__(1024, 1) void mlp_big(
    const void* __restrict__ Xv,
    const short* __restrict__ W1f, const float* __restrict__ b1,
    const short* __restrict__ W2f, const float* __restrict__ b2,
    float* __restrict__ y, ushort* __restrict__ bfout, int nrows) {
  __shared__ alignas(16) short tile_[256 * 128];  // 64 KB
  __shared__ alignas(16) short wb1[16384];        // 32 KB
  __shared__ alignas(16) short wb2[16384];        // 32 KB
  char* tb = reinterpret_cast<char*>(tile_);
  const int tid = threadIdx.x;
  const int lane = tid & 63;
  const int wave = tid >> 6;  // 0..15
  const int row0 = blockIdx.x * 256;
  const int wbase = wave * 16;

  wcopy<2048, 1024>(wb1, W1f, tid);
  wcopy<2048, 1024>(wb2, W2f, tid);
  __syncthreads();  // the only block barrier

  if constexpr (INBF16) {
    const ushort* X = (const ushort*)Xv;
#pragma unroll
    for (int it = 0; it < 4; ++it) {
      int idx = it * 64 + lane;
      int r = wbase + (idx >> 4);
      int c = idx & 15;
      int gr = row0 + r;
      bf16x8 v = {};
      if (gr < nrows) v = *reinterpret_cast<const bf16x8*>(X + (size_t)gr * 128 + c * 8);
      int off = (r * 256 + c * 16) ^ ((r & 7) << 4);
      *reinterpret_cast<bf16x8*>(tb + off) = v;
    }
  } else {
    const float* X = (const float*)Xv;
#pragma unroll
    for (int it = 0; it < 8; ++it) {
      int idx = it * 64 + lane;
      int r = wbase + (idx >> 5);
      int c = idx & 31;
      int gr = row0 + r;
      float4 v = make_float4(0.f, 0.f, 0.f, 0.f);
      if (gr < nrows) v = *reinterpret_cast<const float4*>(X + (size_t)gr * 128 + c * 4);
      short4 p;
      p.x = f2bf(v.x); p.y = f2bf(v.y); p.z = f2bf(v.z); p.w = f2bf(v.w);
      int off = (r * 256 + c * 8) ^ ((r & 7) << 4);
      *reinterpret_cast<short4*>(tb + off) = p;
    }
  }

  // GEMM1 (K=128) -> relu -> in place
  f32x4 acc[8];
  zero16(acc);
  gemm16<4, 8>(tb, wb1, wbase, lane, acc);
  epi16<8, true>(tb, wbase, lane, b1, acc);

  // GEMM2
  f32x4 acc2[8];
  zero16(acc2);
  gemm16<4, 8>(tb, wb2, wbase, lane, acc2);

#pragma unroll
  for (int t = 0; t < 8; ++t) {
    int col = t * 16 + (lane & 15);
    float bb = b2[col];
#pragma unroll
    for (int i = 0; i < 4; ++i) {
      int row = wbase + (lane >> 4) * 4 + i;
      int gr = row0 + row;
      if (gr < nrows) {
        float v = acc2[t][i] + bb;
        if constexpr (SKIP) v += y[(size_t)gr * 128 + col];
        if constexpr (WY) y[(size_t)gr * 128 + col] = v;
        int off = (row * 256 + col * 2) ^ ((row & 7) << 4);
        *reinterpret_cast<short*>(tb + off) = f2bf(v);
      }
    }
  }
#pragma unroll
  for (int rr = 0; rr < 16; ++rr) {
    int row = wbase + rr;
    int gr = row0 + row;
    if (gr < nrows) {
      int off = (row * 256 + lane * 4) ^ ((row & 7) << 4);
      unsigned int v = *reinterpret_cast<const unsigned int*>(tb + off);
      *reinterpret_cast<unsigned int*>(bfout + (size_t)gr * 128 + lane * 2) = v;
    }
  }
}

// ---------- merged tail: gridDim.y selects k1 / k2 / h ----------
__global__ __launch_bounds__(1024, 1) void mlp_tail3(
    const ushort* __restrict__ X,
    const short* __restrict__ k1W1f, const float* __restrict__ k1b1,
    const short* __restrict__ k1W2f, const float* __restrict__ k1b2,
    const short* __restrict__ k2W1f, const float* __restrict__ k2b1,
    const short* __restrict__ k2W2f, const float* __restrict__ k2b2,
    const short* __restrict__ hW1f, const float* __restrict__ hb1,
    const short* __restrict__ hW2f, const float* __restrict__ hb2,
    ushort* __restrict__ u1b, ushort* __restrict__ u2b,
    float* __restrict__ node_out, int nrows) {
  __shared__ alignas(16) short tile_[256 * 128];  // 64 KB
  __shared__ alignas(16) short wb1[16384];        // 32 KB
  __shared__ alignas(16) short wb2[16384];        // 32 KB
  char* tb = reinterpret_cast<char*>(tile_);
  const int tid = threadIdx.x;
  const int lane = tid & 63;
  const int wave = tid >> 6;
  const int row0 = blockIdx.x * 256;
  const int wbase = wave * 16;
  const int mode = blockIdx.y;  // 0: k1->u1b, 1: k2->u2b, 2: h->node_out

  const short* W1f = (mode == 0) ? k1W1f : (mode == 1) ? k2W1f : hW1f;
  const float* b1 = (mode == 0) ? k1b1 : (mode == 1) ? k2b1 : hb1;
  const short* W2f = (mode == 0) ? k1W2f : (mode == 1) ? k2W2f : hW2f;
  const float* b2 = (mode == 0) ? k1b2 : (mode == 1) ? k2b2 : hb2;

  wcopy<2048, 1024>(wb1, W1f, tid);
  if (mode < 2) wcopy<2048, 1024>(wb2, W2f, tid);
  else wcopy<1024, 1024>(wb2, W2f, tid);
  __syncthreads();  // the only block barrier

#pragma unroll
  for (int it = 0; it < 4; ++it) {
    int idx = it * 64 + lane;
    int r = wbase + (idx >> 4);
    int c = idx & 15;
    int gr = row0 + r;
    bf16x8 v = {};
    if (gr < nrows) v = *reinterpret_cast<const bf16x8*>(X + (size_t)gr * 128 + c * 8);
    int off = (r * 256 + c * 16) ^ ((r & 7) << 4);
    *reinterpret_cast<bf16x8*>(tb + off) = v;
  }

  f32x4 acc[8];
  zero16(acc);
  gemm16<4, 8>(tb, wb1, wbase, lane, acc);
  epi16<8, true>(tb, wbase, lane, b1, acc);

  if (mode < 2) {
    f32x4 acc2[8];
    zero16(acc2);
    gemm16<4, 8>(tb, wb2, wbase, lane, acc2);
    epi16<8, false>(tb, wbase, lane, b2, acc2);
    ushort* ub = (mode == 0) ? u1b : u2b;
#pragma unroll
    for (int rr = 0; rr < 16; ++rr) {
      int row = wbase + rr;
      int gr = row0 + row;
      if (gr < nrows) {
        int off = (row * 256 + lane * 4) ^ ((row & 7) << 4);
        unsigned int v = *reinterpret_cast<const unsigned int*>(tb + off);
        *reinterpret_cast<unsigned int*>(ub + (size_t)gr * 128 + lane * 2) = v;
      }
    }
  } else {
    f32x4 acc2[4];
    zero16(acc2);
    gemm16<4, 4>(tb, wb2, wbase, lane, acc2);
#pragma unroll
    for (int t = 0; t < 4; ++t) {
      int col = t * 16 + (lane & 15);
      float bb = b2[col];
#pragma unroll
      for (int i = 0; i < 4; ++i) {
        int row = wbase + (lane >> 4) * 4 + i;
        int gr = row0 + row;
        if (gr < nrows) node_out[(size_t)gr * 64 + col] = acc2[t][i] + bb;
      }
    }
  }
}

// ---------- edge kernel: persistent, 1024 thr, 16 waves x 16 edges ----------
__device__ __forceinline__ void load_tile_regs(const float* __restrict__ xe,
                                               const int* __restrict__ esrc,
                                               const int* __restrict__ edst,
                                               int ebase, int lane,
                                               int& vint, float4 (&xr)[4]) {
  vint = (lane < 32) ? esrc[ebase + (lane & 15)] : edst[ebase + (lane & 15)];
#pragma unroll
  for (int i = 0; i < 4; ++i) {
    int idx = i * 64 + lane;
    int r = idx >> 4, c = idx & 15;
    xr[i] = *reinterpret_cast<const float4*>(xe + (size_t)(ebase + r) * 64 + c * 4);
  }
}

__global__ __launch_bounds__(1024, 1) void edge_kernel(
    const float* __restrict__ xe, const int* __restrict__ esrc,
    const int* __restrict__ edst, const ushort* __restrict__ u1b,
    const ushort* __restrict__ u2b,
    const short* __restrict__ kW1f, const float* __restrict__ kb1,
    const short* __restrict__ kW2f, const float* __restrict__ kb2,
    const short* __restrict__ lW1f, const float* __restrict__ lb1,
    const short* __restrict__ lW2f, const float* __restrict__ lb2,
    float* __restrict__ out) {
  __shared__ alignas(16) short wK1[8192];        // 16 KB (K=64, N=128)
  __shared__ alignas(16) short wK2[16384];       // 32 KB
  __shared__ alignas(16) short wL1[16384];       // 32 KB
  __shared__ alignas(16) short wL2[4096];        // 8 KB  (K=128, N=32)
  __shared__ alignas(16) short tile_[256 * 128]; // 64 KB
  __shared__ float biasL[416];                   // kb1|kb2|lb1|lb2
  char* tb = reinterpret_cast<char*>(tile_);
  const int tid = threadIdx.x;
  const int lane = tid & 63;
  const int wave = tid >> 6;  // 0..15
  const int f4 = lane & 31;
  const int hs = lane >> 5;
  const int wbase = wave * 16;

  wcopy<1024, 1024>(wK1, kW1f, tid);
  wcopy<2048, 1024>(wK2, kW2f, tid);
  wcopy<2048, 1024>(wL1, lW1f, tid);
  wcopy<512, 1024>(wL2, lW2f, tid);
  if (tid < 128) biasL[tid] = kb1[tid];
  else if (tid < 256) biasL[tid] = kb2[tid - 128];
  else if (tid < 384) biasL[tid] = lb1[tid - 256];
  else if (tid < 416) biasL[tid] = lb2[tid - 384];
  __syncthreads();  // the only block barrier

  constexpr int NTILES = NE / 256;  // 3125
  int tile = blockIdx.x;
  int vnext;
  float4 xr[4];
  load_tile_regs(xe, esrc, edst, tile * 256 + wbase, lane, vnext, xr);

  for (; tile < NTILES; tile += gridDim.x) {
    const int ebase = tile * 256 + wbase;
    const int vcur = vnext;

    // write prefetched xe (bf16) into my 16 rows, cols 0..63
#pragma unroll
    for (int i = 0; i < 4; ++i) {
      int idx = i * 64 + lane;
      int r = idx >> 4, c = idx & 15;
      short4 p;
      p.x = f2bf(xr[i].x); p.y = f2bf(xr[i].y);
      p.z = f2bf(xr[i].z); p.w = f2bf(xr[i].w);
      int rr = wbase + r;
      int off = (rr * 256 + c * 8) ^ ((rr & 7) << 4);
      *reinterpret_cast<short4*>(tb + off) = p;
    }

    // gather chunk A (local rows i*2+hs, i<4)
    ushort4 ga[4], gb[4];
#pragma unroll
    for (int i = 0; i < 4; ++i) {
      int s = __shfl(vcur, i * 2 + hs);
      int d = __shfl(vcur, 32 + i * 2 + hs);
      ga[i] = *reinterpret_cast<const ushort4*>(u1b + (size_t)s * 128 + f4 * 4);
      gb[i] = *reinterpret_cast<const ushort4*>(u2b + (size_t)d * 128 + f4 * 4);
    }

    // k GEMM1 (K=64) — split halves + deferred write (register-pressure fix)
    gemm128_inplace<2, true>(tb, wK1, wbase, lane, &biasL[0]);

    // issue chunk B; combine chunk A -> gsumA (frees ga/gb)
    ushort4 ga2[4], gb2[4];
#pragma unroll
    for (int i = 0; i < 4; ++i) {
      int s = __shfl(vcur, (4 + i) * 2 + hs);
      int d = __shfl(vcur, 32 + (4 + i) * 2 + hs);
      ga2[i] = *reinterpret_cast<const ushort4*>(u1b + (size_t)s * 128 + f4 * 4);
      gb2[i] = *reinterpret_cast<const ushort4*>(u2b + (size_t)d * 128 + f4 * 4);
    }
    uint2 gsumA[4];
#pragma unroll
    for (int i = 0; i < 4; ++i) {
      float s0 = bf2f((short)ga[i].x) + bf2f((short)gb[i].x);
      float s1 = bf2f((short)ga[i].y) + bf2f((short)gb[i].y);
      float s2 = bf2f((short)ga[i].z) + bf2f((short)gb[i].z);
      float s3 = bf2f((short)ga[i].w) + bf2f((short)gb[i].w);
      gsumA[i] = make_uint2(pkbf2(s0, s1), pkbf2(s2, s3));
    }

    // k GEMM2 (K=128) — split halves + deferred write
    gemm128_inplace<4, false>(tb, wK2, wbase, lane, &biasL[128]);

    uint2 gsumB[4];
#pragma unroll
    for (int i = 0; i < 4; ++i) {
      float s0 = bf2f((short)ga2[i].x) + bf2f((short)gb2[i].x);
      float s1 = bf2f((short)ga2[i].y) + bf2f((short)gb2[i].y);
      float s2 = bf2f((short)ga2[i].z) + bf2f((short)gb2[i].z);
      float s3 = bf2f((short)ga2[i].w) + bf2f((short)gb2[i].w);
      gsumB[i] = make_uint2(pkbf2(s0, s1), pkbf2(s2, s3));
    }

    // e_hid += u1[src] + u2[dst]  (wave-private rows)
#pragma unroll
    for (int i = 0; i < 8; ++i) {
      int r = wbase + i * 2 + hs;
      int off = (r * 256 + f4 * 8) ^ ((r & 7) << 4);
      short4 c = *reinterpret_cast<short4*>(tb + off);
      uint2 g = (i < 4) ? gsumA[i] : gsumB[i - 4];
      short4 nw;
      nw.x = f2bf(bf2f(c.x) + bf2f((short)(g.x & 0xffff)));
      nw.y = f2bf(bf2f(c.y) + bf2f((short)(g.x >> 16)));
      nw.z = f2bf(bf2f(c.z) + bf2f((short)(g.y & 0xffff)));
      nw.w = f2bf(bf2f(c.w) + bf2f((short)(g.y >> 16)));
      *reinterpret_cast<short4*>(tb + off) = nw;
    }

    // prefetch next tile's xe + endpoints (hides under GEMM3/4)
    int nt2 = tile + gridDim.x;
    if (nt2 < NTILES)
      load_tile_regs(xe, esrc, edst, nt2 * 256 + wbase, lane, vnext, xr);

    // l GEMM3 (K=128) — split halves + deferred write
    gemm128_inplace<4, true>(tb, wL1, wbase, lane, &biasL[256]);

    // l GEMM4 (K=128, N=32)
    f32x4 acc4[2];
    zero16(acc4);
    gemm16<4, 2>(tb, wL2, wbase, lane, acc4);

    // direct output stores (r7 layout — best measured)
#pragma unroll
    for (int t = 0; t < 2; ++t) {
      int col = t * 16 + (lane & 15);
      float bb = biasL[384 + col];
#pragma unroll
      for (int i = 0; i < 4; ++i) {
        int row = (lane >> 4) * 4 + i;
        out[(size_t)(ebase + row) * 32 + col] = acc4[t][i] + bb;
      }
    }
  }
}

}  // namespace

extern "C" void kernel_launch(void* const* d_in, const int* in_sizes, int n_in,
                              void* d_out, int out_size, void* d_ws, size_t ws_size,
                              hipStream_t stream) {
  const float* x = (const float*)d_in[0];
  const float* xe = (const float*)d_in[1];
  const int* eidx = (const int*)d_in[2];
  const int* esrc = eidx;
  const int* edst = eidx + NE;

  const float* fb1 = (const float*)d_in[4];
  const float* fb2 = (const float*)d_in[6];
  const float* gb1 = (const float*)d_in[8];
  const float* gb2 = (const float*)d_in[10];
  const float* hb1 = (const float*)d_in[12];
  const float* hb2 = (const float*)d_in[14];
  const float* k1b1 = (const float*)d_in[16];
  const float* k1b2 = (const float*)d_in[18];
  const float* k2b1 = (const float*)d_in[20];
  const float* k2b2 = (const float*)d_in[22];
  const float* kb1 = (const float*)d_in[24];
  const float* kb2 = (const float*)d_in[26];
  const float* lb1 = (const float*)d_in[28];
  const float* lb2 = (const float*)d_in[30];

  char* ws = (char*)d_ws;
  size_t off = 0;
  auto alloc = [&](size_t bytes) -> void* {
    void* p = ws + off;
    off = (off + bytes + 255) & ~(size_t)255;
    return p;
  };
  float* y = (float*)alloc((size_t)NN * 128 * 4);
  ushort* ybA = (ushort*)alloc((size_t)NN * 128 * 2);
  ushort* ybB = (ushort*)alloc((size_t)NN * 128 * 2);
  ushort* aggb = (ushort*)alloc((size_t)NN * 128 * 2);
  ushort* u1b = (ushort*)alloc((size_t)NN * 128 * 2);
  ushort* u2b = (ushort*)alloc((size_t)NN * 128 * 2);
  int* deg = (int*)alloc((size_t)NN * 4);
  int* excl = (int*)alloc((size_t)NN * 4);
  int* bsum = (int*)alloc(256 * 4);
  int* boff = (int*)alloc(256 * 4);
  int* row_start = (int*)alloc((size_t)(NN + 16) * 4);
  int* cursor = (int*)alloc((size_t)NN * 4);
  int* adj = (int*)alloc((size_t)NE * 4);

  // weight fragment buffers (single fused repack launch)
  const int wi[14] = {3, 5, 7, 9, 11, 13, 15, 17, 19, 21, 23, 25, 27, 29};
  const int wdin[14] = {128, 128, 128, 128, 128, 128, 128, 128, 128, 128, 64, 128, 128, 128};
  const int wdout[14] = {128, 128, 128, 128, 128, 64, 128, 128, 128, 128, 128, 128, 128, 32};
  WTab tab;
  short* wf[14];
  for (int i = 0; i < 14; ++i) {
    size_t elems = (size_t)wdin[i] * wdout[i];
    wf[i] = (short*)alloc(elems * 2);
    tab.W[i] = (const float*)d_in[wi[i]];
    tab.out[i] = wf[i];
    tab.din[i] = wdin[i];
    tab.dout[i] = wdout[i];
  }
  wfrag_all<<<dim3(64, 14, 1), 256, 0, stream>>>(tab);

  short* fW1f = wf[0];  short* fW2f = wf[1];
  short* gW1f = wf[2];  short* gW2f = wf[3];
  short* hW1f = wf[4];  short* hW2f = wf[5];
  short* k1W1f = wf[6]; short* k1W2f = wf[7];
  short* k2W1f = wf[8]; short* k2W2f = wf[9];
  short* kW1f = wf[10]; short* kW2f = wf[11];
  short* lW1f = wf[12]; short* lW2f = wf[13];

  // CSR build
  const int nb = (NN + 255) / 256;  // 196
  hipMemsetAsync(deg, 0, (size_t)NN * 4, stream);
  hist_kernel<<<(NE + 255) / 256, 256, 0, stream>>>(edst, deg);
  scan1_kernel<<<nb, 256, 0, stream>>>(deg, excl, bsum, NN);
  scan2_kernel<<<1, 256, 0, stream>>>(bsum, boff, nb);
  scan3_kernel<<<(NN + 256) / 256 + 1, 256, 0, stream>>>(excl, boff, row_start, NN, nb);
  hipMemsetAsync(cursor, 0, (size_t)NN * 4, stream);
  fill_kernel<<<(NE + 255) / 256, 256, 0, stream>>>(esrc, edst, row_start, cursor, adj);

  const int nblk = (NN + 255) / 256;  // 196 tiles of 256 rows

  // y = f(x): f32 y + bf16 ybA
  mlp_big<false, false, true><<<nblk, 1024, 0, stream>>>(
      x, fW1f, fb1, fW2f, fb2, y, ybA, NN);

  // 3 MP steps: agg (parallel CSR gather) then g; last step skips dead y-write
  ushort* ybin = ybA;
  ushort* ybout = ybB;
  for (int s = 0; s < 3; ++s) {
    agg_kernel<<<(NN / 4 * 64) / 256, 256, 0, stream>>>(ybin, row_start, adj, aggb);
    if (s < 2)
      mlp_big<true, true, true><<<nblk, 1024, 0, stream>>>(
          aggb, gW1f, gb1, gW2f, gb2, y, ybout, NN);
    else
      mlp_big<true, true, false><<<nblk, 1024, 0, stream>>>(
          aggb, gW1f, gb1, gW2f, gb2, y, ybout, NN);
    ushort* t = ybin; ybin = ybout; ybout = t;
  }

  // u1 = k1(y), u2 = k2(y), node_out = h(y) — one merged launch, 588 blocks
  mlp_tail3<<<dim3(nblk, 3), 1024, 0, stream>>>(
      ybin, k1W1f, k1b1, k1W2f, k1b2, k2W1f, k2b1, k2W2f, k2b2,
      hW1f, hb1, hW2f, hb2, u1b, u2b, (float*)d_out, NN);

  // edge_out = l(k(xe) + u1[src] + u2[dst])  — persistent, 256 blocks
  float* edge_out = (float*)d_out + (size_t)NN * 64;
  edge_kernel<<<256, 1024, 0, stream>>>(xe, esrc, edst, u1b, u2b, kW1f, kb1, kW2f, kb2,
                                        lW1f, lb1, lW2f, lb2, edge_out);
}

// Round 13
// 546.689 us; speedup vs baseline: 1.1249x; 1.0251x over previous
//
#include <hip/hip_runtime.h>
#include <hip/hip_bf16.h>

namespace {

constexpr int NN = 50000;
constexpr int NE = 800000;

typedef __attribute__((ext_vector_type(8))) short bf16x8;
typedef __attribute__((ext_vector_type(4))) float f32x4;

__device__ __forceinline__ short f2bf(float f) {
  union { __hip_bfloat16 h; short s; } u;
  u.h = __float2bfloat16(f);
  return u.s;
}
__device__ __forceinline__ float bf2f(short s) {
  union { unsigned int u; float f; } v;
  v.u = ((unsigned int)(unsigned short)s) << 16;
  return v.f;
}
__device__ __forceinline__ unsigned int pkbf2(float a, float b) {
  return (unsigned int)(unsigned short)f2bf(a) |
         ((unsigned int)(unsigned short)f2bf(b) << 16);
}

// ---------- weight repack (all 14 in one launch) ----------
struct WTab {
  const float* W[14];
  short* out[14];
  int din[14];
  int dout[14];
};

__global__ __launch_bounds__(256) void wfrag_all(WTab tab) {
  int wi = blockIdx.y;
  int din = tab.din[wi], dout = tab.dout[wi];
  int total = din * dout;
  int gid = blockIdx.x * 256 + threadIdx.x;
  if (gid >= total) return;
  const float* W = tab.W[wi];
  short* Wf = tab.out[wi];
  int j = gid & 7;
  int l = (gid >> 3) & 63;
  int rest = gid >> 9;
  int nK = din >> 5;
  int kc = rest % nK;
  int t = rest / nK;
  int n = t * 16 + (l & 15);
  int k = kc * 32 + (l >> 4) * 8 + j;
  Wf[gid] = f2bf(W[(size_t)k * dout + n]);
}

// ---------- CSR build ----------
__global__ __launch_bounds__(256) void hist_kernel(const int* __restrict__ edst,
                                                   int* __restrict__ deg) {
  int e = blockIdx.x * 256 + threadIdx.x;
  if (e < NE) atomicAdd(&deg[edst[e]], 1);
}

__global__ __launch_bounds__(256) void scan1_kernel(const int* __restrict__ deg,
                                                    int* __restrict__ excl,
                                                    int* __restrict__ bsum, int N) {
  __shared__ int s[256];
  int tid = threadIdx.x;
  int i = blockIdx.x * 256 + tid;
  int v = (i < N) ? deg[i] : 0;
  s[tid] = v;
  __syncthreads();
  for (int d = 1; d < 256; d <<= 1) {
    int t = (tid >= d) ? s[tid - d] : 0;
    __syncthreads();
    s[tid] += t;
    __syncthreads();
  }
  if (i < N) excl[i] = s[tid] - v;
  if (tid == 255) bsum[blockIdx.x] = s[255];
}

__global__ __launch_bounds__(256) void scan2_kernel(const int* __restrict__ bsum,
                                                    int* __restrict__ boff, int nb) {
  __shared__ int s[256];
  int tid = threadIdx.x;
  int v = (tid < nb) ? bsum[tid] : 0;
  s[tid] = v;
  __syncthreads();
  for (int d = 1; d < 256; d <<= 1) {
    int t = (tid >= d) ? s[tid - d] : 0;
    __syncthreads();
    s[tid] += t;
    __syncthreads();
  }
  if (tid <= nb) boff[tid] = s[tid] - v;
}

__global__ __launch_bounds__(256) void scan3_kernel(const int* __restrict__ excl,
                                                    const int* __restrict__ boff,
                                                    int* __restrict__ row_start,
                                                    int N, int nb) {
  int i = blockIdx.x * 256 + threadIdx.x;
  if (i < N) row_start[i] = excl[i] + boff[i >> 8];
  else if (i == N) row_start[N] = boff[nb];
}

__global__ __launch_bounds__(256) void fill_kernel(const int* __restrict__ esrc,
                                                   const int* __restrict__ edst,
                                                   const int* __restrict__ row_start,
                                                   int* __restrict__ cursor,
                                                   int* __restrict__ adj) {
  int e = blockIdx.x * 256 + threadIdx.x;
  if (e >= NE) return;
  int d = edst[e];
  int p = atomicAdd(&cursor[d], 1);
  adj[row_start[d] + p] = esrc[e];
}

// ---------- segment-sum: 4 nodes/wave, 16 lanes per node ----------
__global__ __launch_bounds__(256) void agg_kernel(const ushort* __restrict__ yb,
                                                  const int* __restrict__ row_start,
                                                  const int* __restrict__ adj,
                                                  ushort* __restrict__ aggb) {
  int gid = blockIdx.x * 256 + threadIdx.x;
  int lane = gid & 63;
  int g = lane >> 4;
  int q = lane & 15;
  int n = (gid >> 6) * 4 + g;
  int s0 = row_start[n], s1 = row_start[n + 1];
  float a0 = 0, a1 = 0, a2 = 0, a3 = 0, a4 = 0, a5 = 0, a6 = 0, a7 = 0;
  for (int base = s0; base < s1; base += 16) {
    int idx = 0;
    if (base + q < s1) idx = adj[base + q];
    int cnt = s1 - base;
    if (cnt > 16) cnt = 16;
#pragma unroll
    for (int j = 0; j < 16; ++j) {
      if (j < cnt) {
        int s = __shfl(idx, g * 16 + j);
        uint4 v = *reinterpret_cast<const uint4*>(yb + (size_t)s * 128 + q * 8);
        a0 += bf2f((short)(v.x & 0xffff)); a1 += bf2f((short)(v.x >> 16));
        a2 += bf2f((short)(v.y & 0xffff)); a3 += bf2f((short)(v.y >> 16));
        a4 += bf2f((short)(v.z & 0xffff)); a5 += bf2f((short)(v.z >> 16));
        a6 += bf2f((short)(v.w & 0xffff)); a7 += bf2f((short)(v.w >> 16));
      }
    }
  }
  uint4 o;
  o.x = pkbf2(a0, a1);
  o.y = pkbf2(a2, a3);
  o.z = pkbf2(a4, a5);
  o.w = pkbf2(a6, a7);
  *reinterpret_cast<uint4*>(aggb + (size_t)n * 128 + q * 8) = o;
}

// ---------- MFMA helpers ----------
// A tile: [rows][128 bf16 cols], row stride 256B, XOR swizzle ((row&7)<<4).
// B weights LDS layout == global fragment layout: granule (t*NKC+kc)*64+lane.

template <int NG, int NTHR>
__device__ __forceinline__ void wcopy(short* dst, const short* __restrict__ src,
                                      int tid) {
#pragma unroll
  for (int g0 = 0; g0 < NG; g0 += NTHR) {
    int g = g0 + tid;
    if (g < NG)
      *reinterpret_cast<bf16x8*>(dst + (size_t)g * 8) =
          *reinterpret_cast<const bf16x8*>(src + (size_t)g * 8);
  }
}

// NM=1 GEMM: one 16-row m-tile per wave, B from LDS; setprio around MFMA (T5).
template <int KCPH, int NT>
__device__ __forceinline__ void gemm16(const char* tb, const short* wbuf,
                                       int rbase, int lane, f32x4 (&acc)[NT]) {
#pragma unroll
  for (int kc = 0; kc < KCPH; ++kc) {
    int row = rbase + (lane & 15);
    int off = (row * 256 + kc * 64 + (lane >> 4) * 16) ^ ((row & 7) << 4);
    bf16x8 a = *reinterpret_cast<const bf16x8*>(tb + off);
    __builtin_amdgcn_s_setprio(1);
#pragma unroll
    for (int t = 0; t < NT; ++t) {
      bf16x8 b = *reinterpret_cast<const bf16x8*>(wbuf + ((size_t)((t * KCPH + kc) * 64 + lane)) * 8);
      acc[t] = __builtin_amdgcn_mfma_f32_16x16x32_bf16(a, b, acc[t], 0, 0, 0);
    }
    __builtin_amdgcn_s_setprio(0);
  }
}

template <int NT>
__device__ __forceinline__ void zero16(f32x4 (&acc)[NT]) {
  const f32x4 vzero = {0.f, 0.f, 0.f, 0.f};
#pragma unroll
  for (int t = 0; t < NT; ++t) acc[t] = vzero;
}

// epilogue for 16-row wave tile; bias pointer may be global or LDS
template <int NT, bool RELU>
__device__ __forceinline__ void epi16(char* dst, int rbase, int lane,
                                      const float* bias, f32x4 (&acc)[NT]) {
#pragma unroll
  for (int t = 0; t < NT; ++t) {
    int col = t * 16 + (lane & 15);
    float bb = bias[col];
#pragma unroll
    for (int i = 0; i < 4; ++i) {
      int row = rbase + (lane >> 4) * 4 + i;
      float h = acc[t][i] + bb;
      if (RELU) h = fmaxf(h, 0.f);
      int off = (row * 256 + col * 2) ^ ((row & 7) << 4);
      *reinterpret_cast<short*>(dst + off) = f2bf(h);
    }
  }
}

// ---------- node MLP f/g: 1024 thr, 16 waves x 16 rows, weights LDS-resident ----------
// SKIP: bf16 residual add from skipb (removes the f32 y buffer entirely).
template <bool INBF16, bool SKIP>
__global__ __launch_bounds__(1024, 1) void mlp_big(
    const void* __restrict__ Xv,
    const short* __restrict__ W1f, const float* __restrict__ b1,
    const short* __restrict__ W2f, const float* __restrict__ b2,
    const ushort* __restrict__ skipb, ushort* __restrict__ bfout, int nrows) {
  __shared__ alignas(16) short tile_[256 * 128];  // 64 KB
  __shared__ alignas(16) short wb1[16384];        // 32 KB
  __shared__ alignas(16) short wb2[16384];        // 32 KB
  char* tb = reinterpret_cast<char*>(tile_);
  const int tid = threadIdx.x;
  const int lane = tid & 63;
  const int wave = tid >> 6;  // 0..15
  const int row0 = blockIdx.x * 256;
  const int wbase = wave * 16;

  wcopy<2048, 1024>(wb1, W1f, tid);
  wcopy<2048, 1024>(wb2, W2f, tid);
  __syncthreads();  // the only block barrier

  if constexpr (INBF16) {
    const ushort* X = (const ushort*)Xv;
#pragma unroll
    for (int it = 0; it < 4; ++it) {
      int idx = it * 64 + lane;
      int r = wbase + (idx >> 4);
      int c = idx & 15;
      int gr = row0 + r;
      bf16x8 v = {};
      if (gr < nrows) v = *reinterpret_cast<const bf16x8*>(X + (size_t)gr * 128 + c * 8);
      int off = (r * 256 + c * 16) ^ ((r & 7) << 4);
      *reinterpret_cast<bf16x8*>(tb + off) = v;
    }
  } else {
    const float* X = (const float*)Xv;
#pragma unroll
    for (int it = 0; it < 8; ++it) {
      int idx = it * 64 + lane;
      int r = wbase + (idx >> 5);
      int c = idx & 31;
      int gr = row0 + r;
      float4 v = make_float4(0.f, 0.f, 0.f, 0.f);
      if (gr < nrows) v = *reinterpret_cast<const float4*>(X + (size_t)gr * 128 + c * 4);
      short4 p;
      p.x = f2bf(v.x); p.y = f2bf(v.y); p.z = f2bf(v.z); p.w = f2bf(v.w);
      int off = (r * 256 + c * 8) ^ ((r & 7) << 4);
      *reinterpret_cast<short4*>(tb + off) = p;
    }
  }

  // GEMM1 (K=128) -> relu -> in place
  f32x4 acc[8];
  zero16(acc);
  gemm16<4, 8>(tb, wb1, wbase, lane, acc);
  epi16<8, true>(tb, wbase, lane, b1, acc);

  // GEMM2
  f32x4 acc2[8];
  zero16(acc2);
  gemm16<4, 8>(tb, wb2, wbase, lane, acc2);

#pragma unroll
  for (int t = 0; t < 8; ++t) {
    int col = t * 16 + (lane & 15);
    float bb = b2[col];
#pragma unroll
    for (int i = 0; i < 4; ++i) {
      int row = wbase + (lane >> 4) * 4 + i;
      int gr = row0 + row;
      if (gr < nrows) {
        float v = acc2[t][i] + bb;
        if constexpr (SKIP)
          v += bf2f((short)skipb[(size_t)gr * 128 + col]);
        int off = (row * 256 + col * 2) ^ ((row & 7) << 4);
        *reinterpret_cast<short*>(tb + off) = f2bf(v);
      }
    }
  }
  // coalesced bf16 store of this wave's 16 rows
#pragma unroll
  for (int rr = 0; rr < 16; ++rr) {
    int row = wbase + rr;
    int gr = row0 + row;
    if (gr < nrows) {
      int off = (row * 256 + lane * 4) ^ ((row & 7) << 4);
      unsigned int v = *reinterpret_cast<const unsigned int*>(tb + off);
      *reinterpret_cast<unsigned int*>(bfout + (size_t)gr * 128 + lane * 2) = v;
    }
  }
}

// ---------- merged tail: gridDim.y selects k1 / k2 / h ----------
__global__ __launch_bounds__(1024, 1) void mlp_tail3(
    const ushort* __restrict__ X,
    const short* __restrict__ k1W1f, const float* __restrict__ k1b1,
    const short* __restrict__ k1W2f, const float* __restrict__ k1b2,
    const short* __restrict__ k2W1f, const float* __restrict__ k2b1,
    const short* __restrict__ k2W2f, const float* __restrict__ k2b2,
    const short* __restrict__ hW1f, const float* __restrict__ hb1,
    const short* __restrict__ hW2f, const float* __restrict__ hb2,
    ushort* __restrict__ u1b, ushort* __restrict__ u2b,
    float* __restrict__ node_out, int nrows) {
  __shared__ alignas(16) short tile_[256 * 128];  // 64 KB
  __shared__ alignas(16) short wb1[16384];        // 32 KB
  __shared__ alignas(16) short wb2[16384];        // 32 KB
  char* tb = reinterpret_cast<char*>(tile_);
  const int tid = threadIdx.x;
  const int lane = tid & 63;
  const int wave = tid >> 6;
  const int row0 = blockIdx.x * 256;
  const int wbase = wave * 16;
  const int mode = blockIdx.y;  // 0: k1->u1b, 1: k2->u2b, 2: h->node_out

  const short* W1f = (mode == 0) ? k1W1f : (mode == 1) ? k2W1f : hW1f;
  const float* b1 = (mode == 0) ? k1b1 : (mode == 1) ? k2b1 : hb1;
  const short* W2f = (mode == 0) ? k1W2f : (mode == 1) ? k2W2f : hW2f;
  const float* b2 = (mode == 0) ? k1b2 : (mode == 1) ? k2b2 : hb2;

  wcopy<2048, 1024>(wb1, W1f, tid);
  if (mode < 2) wcopy<2048, 1024>(wb2, W2f, tid);
  else wcopy<1024, 1024>(wb2, W2f, tid);
  __syncthreads();  // the only block barrier

#pragma unroll
  for (int it = 0; it < 4; ++it) {
    int idx = it * 64 + lane;
    int r = wbase + (idx >> 4);
    int c = idx & 15;
    int gr = row0 + r;
    bf16x8 v = {};
    if (gr < nrows) v = *reinterpret_cast<const bf16x8*>(X + (size_t)gr * 128 + c * 8);
    int off = (r * 256 + c * 16) ^ ((r & 7) << 4);
    *reinterpret_cast<bf16x8*>(tb + off) = v;
  }

  f32x4 acc[8];
  zero16(acc);
  gemm16<4, 8>(tb, wb1, wbase, lane, acc);
  epi16<8, true>(tb, wbase, lane, b1, acc);

  if (mode < 2) {
    f32x4 acc2[8];
    zero16(acc2);
    gemm16<4, 8>(tb, wb2, wbase, lane, acc2);
    epi16<8, false>(tb, wbase, lane, b2, acc2);
    ushort* ub = (mode == 0) ? u1b : u2b;
#pragma unroll
    for (int rr = 0; rr < 16; ++rr) {
      int row = wbase + rr;
      int gr = row0 + row;
      if (gr < nrows) {
        int off = (row * 256 + lane * 4) ^ ((row & 7) << 4);
        unsigned int v = *reinterpret_cast<const unsigned int*>(tb + off);
        *reinterpret_cast<unsigned int*>(ub + (size_t)gr * 128 + lane * 2) = v;
      }
    }
  } else {
    f32x4 acc2[4];
    zero16(acc2);
    gemm16<4, 4>(tb, wb2, wbase, lane, acc2);
#pragma unroll
    for (int t = 0; t < 4; ++t) {
      int col = t * 16 + (lane & 15);
      float bb = b2[col];
#pragma unroll
      for (int i = 0; i < 4; ++i) {
        int row = wbase + (lane >> 4) * 4 + i;
        int gr = row0 + row;
        if (gr < nrows) node_out[(size_t)gr * 64 + col] = acc2[t][i] + bb;
      }
    }
  }
}

// ---------- edge kernel: persistent, 1024 thr, 16 waves x 16 edges (r7 exact) ----------
__device__ __forceinline__ void load_tile_regs(const float* __restrict__ xe,
                                               const int* __restrict__ esrc,
                                               const int* __restrict__ edst,
                                               int ebase, int lane,
                                               int& vint, float4 (&xr)[4]) {
  vint = (lane < 32) ? esrc[ebase + (lane & 15)] : edst[ebase + (lane & 15)];
#pragma unroll
  for (int i = 0; i < 4; ++i) {
    int idx = i * 64 + lane;
    int r = idx >> 4, c = idx & 15;
    xr[i] = *reinterpret_cast<const float4*>(xe + (size_t)(ebase + r) * 64 + c * 4);
  }
}

__global__ __launch_bounds__(1024, 1) void edge_kernel(
    const float* __restrict__ xe, const int* __restrict__ esrc,
    const int* __restrict__ edst, const ushort* __restrict__ u1b,
    const ushort* __restrict__ u2b,
    const short* __restrict__ kW1f, const float* __restrict__ kb1,
    const short* __restrict__ kW2f, const float* __restrict__ kb2,
    const short* __restrict__ lW1f, const float* __restrict__ lb1,
    const short* __restrict__ lW2f, const float* __restrict__ lb2,
    float* __restrict__ out) {
  __shared__ alignas(16) short wK1[8192];        // 16 KB (K=64, N=128)
  __shared__ alignas(16) short wK2[16384];       // 32 KB
  __shared__ alignas(16) short wL1[16384];       // 32 KB
  __shared__ alignas(16) short wL2[4096];        // 8 KB  (K=128, N=32)
  __shared__ alignas(16) short tile_[256 * 128]; // 64 KB
  __shared__ float biasL[416];                   // kb1|kb2|lb1|lb2
  char* tb = reinterpret_cast<char*>(tile_);
  const int tid = threadIdx.x;
  const int lane = tid & 63;
  const int wave = tid >> 6;  // 0..15
  const int f4 = lane & 31;
  const int hs = lane >> 5;
  const int wbase = wave * 16;

  wcopy<1024, 1024>(wK1, kW1f, tid);
  wcopy<2048, 1024>(wK2, kW2f, tid);
  wcopy<2048, 1024>(wL1, lW1f, tid);
  wcopy<512, 1024>(wL2, lW2f, tid);
  if (tid < 128) biasL[tid] = kb1[tid];
  else if (tid < 256) biasL[tid] = kb2[tid - 128];
  else if (tid < 384) biasL[tid] = lb1[tid - 256];
  else if (tid < 416) biasL[tid] = lb2[tid - 384];
  __syncthreads();  // the only block barrier

  constexpr int NTILES = NE / 256;  // 3125
  int tile = blockIdx.x;
  int vnext;
  float4 xr[4];
  load_tile_regs(xe, esrc, edst, tile * 256 + wbase, lane, vnext, xr);

  for (; tile < NTILES; tile += gridDim.x) {
    const int ebase = tile * 256 + wbase;
    const int vcur = vnext;

    // write prefetched xe (bf16) into my 16 rows, cols 0..63
#pragma unroll
    for (int i = 0; i < 4; ++i) {
      int idx = i * 64 + lane;
      int r = idx >> 4, c = idx & 15;
      short4 p;
      p.x = f2bf(xr[i].x); p.y = f2bf(xr[i].y);
      p.z = f2bf(xr[i].z); p.w = f2bf(xr[i].w);
      int rr = wbase + r;
      int off = (rr * 256 + c * 8) ^ ((rr & 7) << 4);
      *reinterpret_cast<short4*>(tb + off) = p;
    }

    // gather chunk A (local rows i*2+hs, i<4)
    ushort4 ga[4], gb[4];
#pragma unroll
    for (int i = 0; i < 4; ++i) {
      int s = __shfl(vcur, i * 2 + hs);
      int d = __shfl(vcur, 32 + i * 2 + hs);
      ga[i] = *reinterpret_cast<const ushort4*>(u1b + (size_t)s * 128 + f4 * 4);
      gb[i] = *reinterpret_cast<const ushort4*>(u2b + (size_t)d * 128 + f4 * 4);
    }

    // k GEMM1 (K=64)
    f32x4 acc[8];
    zero16(acc);
    gemm16<2, 8>(tb, wK1, wbase, lane, acc);
    epi16<8, true>(tb, wbase, lane, &biasL[0], acc);

    // issue chunk B; combine chunk A
    ushort4 ga2[4], gb2[4];
#pragma unroll
    for (int i = 0; i < 4; ++i) {
      int s = __shfl(vcur, (4 + i) * 2 + hs);
      int d = __shfl(vcur, 32 + (4 + i) * 2 + hs);
      ga2[i] = *reinterpret_cast<const ushort4*>(u1b + (size_t)s * 128 + f4 * 4);
      gb2[i] = *reinterpret_cast<const ushort4*>(u2b + (size_t)d * 128 + f4 * 4);
    }
    uint2 gsum[8];
#pragma unroll
    for (int i = 0; i < 4; ++i) {
      float s0 = bf2f((short)ga[i].x) + bf2f((short)gb[i].x);
      float s1 = bf2f((short)ga[i].y) + bf2f((short)gb[i].y);
      float s2 = bf2f((short)ga[i].z) + bf2f((short)gb[i].z);
      float s3 = bf2f((short)ga[i].w) + bf2f((short)gb[i].w);
      gsum[i] = make_uint2(pkbf2(s0, s1), pkbf2(s2, s3));
    }

    // k GEMM2 (K=128)
    zero16(acc);
    gemm16<4, 8>(tb, wK2, wbase, lane, acc);
    epi16<8, false>(tb, wbase, lane, &biasL[128], acc);

#pragma unroll
    for (int i = 0; i < 4; ++i) {
      float s0 = bf2f((short)ga2[i].x) + bf2f((short)gb2[i].x);
      float s1 = bf2f((short)ga2[i].y) + bf2f((short)gb2[i].y);
      float s2 = bf2f((short)ga2[i].z) + bf2f((short)gb2[i].z);
      float s3 = bf2f((short)ga2[i].w) + bf2f((short)gb2[i].w);
      gsum[4 + i] = make_uint2(pkbf2(s0, s1), pkbf2(s2, s3));
    }

    // e_hid += u1[src] + u2[dst]  (wave-private rows)
#pragma unroll
    for (int i = 0; i < 8; ++i) {
      int r = wbase + i * 2 + hs;
      int off = (r * 256 + f4 * 8) ^ ((r & 7) << 4);
      short4 c = *reinterpret_cast<short4*>(tb + off);
      uint2 g = gsum[i];
      short4 nw;
      nw.x = f2bf(bf2f(c.x) + bf2f((short)(g.x & 0xffff)));
      nw.y = f2bf(bf2f(c.y) + bf2f((short)(g.x >> 16)));
      nw.z = f2bf(bf2f(c.z) + bf2f((short)(g.y & 0xffff)));
      nw.w = f2bf(bf2f(c.w) + bf2f((short)(g.y >> 16)));
      *reinterpret_cast<short4*>(tb + off) = nw;
    }

    // prefetch next tile's xe + endpoints (hides under GEMM3/4)
    int nt2 = tile + gridDim.x;
    if (nt2 < NTILES)
      load_tile_regs(xe, esrc, edst, nt2 * 256 + wbase, lane, vnext, xr);

    // l GEMM3 (K=128)
    zero16(acc);
    gemm16<4, 8>(tb, wL1, wbase, lane, acc);
    epi16<8, true>(tb, wbase, lane, &biasL[256], acc);

    // l GEMM4 (K=128, N=32)
    f32x4 acc4[2];
    zero16(acc4);
    gemm16<4, 2>(tb, wL2, wbase, lane, acc4);

    // direct output stores (r7 layout — best measured)
#pragma unroll
    for (int t = 0; t < 2; ++t) {
      int col = t * 16 + (lane & 15);
      float bb = biasL[384 + col];
#pragma unroll
      for (int i = 0; i < 4; ++i) {
        int row = (lane >> 4) * 4 + i;
        out[(size_t)(ebase + row) * 32 + col] = acc4[t][i] + bb;
      }
    }
  }
}

}  // namespace

extern "C" void kernel_launch(void* const* d_in, const int* in_sizes, int n_in,
                              void* d_out, int out_size, void* d_ws, size_t ws_size,
                              hipStream_t stream) {
  const float* x = (const float*)d_in[0];
  const float* xe = (const float*)d_in[1];
  const int* eidx = (const int*)d_in[2];
  const int* esrc = eidx;
  const int* edst = eidx + NE;

  const float* fb1 = (const float*)d_in[4];
  const float* fb2 = (const float*)d_in[6];
  const float* gb1 = (const float*)d_in[8];
  const float* gb2 = (const float*)d_in[10];
  const float* hb1 = (const float*)d_in[12];
  const float* hb2 = (const float*)d_in[14];
  const float* k1b1 = (const float*)d_in[16];
  const float* k1b2 = (const float*)d_in[18];
  const float* k2b1 = (const float*)d_in[20];
  const float* k2b2 = (const float*)d_in[22];
  const float* kb1 = (const float*)d_in[24];
  const float* kb2 = (const float*)d_in[26];
  const float* lb1 = (const float*)d_in[28];
  const float* lb2 = (const float*)d_in[30];

  char* ws = (char*)d_ws;
  size_t off = 0;
  auto alloc = [&](size_t bytes) -> void* {
    void* p = ws + off;
    off = (off + bytes + 255) & ~(size_t)255;
    return p;
  };
  ushort* ybA = (ushort*)alloc((size_t)NN * 128 * 2);
  ushort* ybB = (ushort*)alloc((size_t)NN * 128 * 2);
  ushort* ybC = (ushort*)alloc((size_t)NN * 128 * 2);
  ushort* aggb = (ushort*)alloc((size_t)NN * 128 * 2);
  ushort* u1b = (ushort*)alloc((size_t)NN * 128 * 2);
  ushort* u2b = (ushort*)alloc((size_t)NN * 128 * 2);
  int* deg = (int*)alloc((size_t)NN * 4);
  int* excl = (int*)alloc((size_t)NN * 4);
  int* bsum = (int*)alloc(256 * 4);
  int* boff = (int*)alloc(256 * 4);
  int* row_start = (int*)alloc((size_t)(NN + 16) * 4);
  int* cursor = (int*)alloc((size_t)NN * 4);
  int* adj = (int*)alloc((size_t)NE * 4);

  // weight fragment buffers (single fused repack launch)
  const int wi[14] = {3, 5, 7, 9, 11, 13, 15, 17, 19, 21, 23, 25, 27, 29};
  const int wdin[14] = {128, 128, 128, 128, 128, 128, 128, 128, 128, 128, 64, 128, 128, 128};
  const int wdout[14] = {128, 128, 128, 128, 128, 64, 128, 128, 128, 128, 128, 128, 128, 32};
  WTab tab;
  short* wf[14];
  for (int i = 0; i < 14; ++i) {
    size_t elems = (size_t)wdin[i] * wdout[i];
    wf[i] = (short*)alloc(elems * 2);
    tab.W[i] = (const float*)d_in[wi[i]];
    tab.out[i] = wf[i];
    tab.din[i] = wdin[i];
    tab.dout[i] = wdout[i];
  }
  wfrag_all<<<dim3(64, 14, 1), 256, 0, stream>>>(tab);

  short* fW1f = wf[0];  short* fW2f = wf[1];
  short* gW1f = wf[2];  short* gW2f = wf[3];
  short* hW1f = wf[4];  short* hW2f = wf[5];
  short* k1W1f = wf[6]; short* k1W2f = wf[7];
  short* k2W1f = wf[8]; short* k2W2f = wf[9];
  short* kW1f = wf[10]; short* kW2f = wf[11];
  short* lW1f = wf[12]; short* lW2f = wf[13];

  // CSR build
  const int nb = (NN + 255) / 256;  // 196
  hipMemsetAsync(deg, 0, (size_t)NN * 4, stream);
  hist_kernel<<<(NE + 255) / 256, 256, 0, stream>>>(edst, deg);
  scan1_kernel<<<nb, 256, 0, stream>>>(deg, excl, bsum, NN);
  scan2_kernel<<<1, 256, 0, stream>>>(bsum, boff, nb);
  scan3_kernel<<<(NN + 256) / 256 + 1, 256, 0, stream>>>(excl, boff, row_start, NN, nb);
  hipMemsetAsync(cursor, 0, (size_t)NN * 4, stream);
  fill_kernel<<<(NE + 255) / 256, 256, 0, stream>>>(esrc, edst, row_start, cursor, adj);

  const int nblk = (NN + 255) / 256;  // 196 tiles of 256 rows

  // y0 = f(x)  (bf16 only — skip chain carried in bf16)
  mlp_big<false, false><<<nblk, 1024, 0, stream>>>(
      x, fW1f, fb1, fW2f, fb2, nullptr, ybA, NN);

  // 3 MP steps: y_{s+1} = g(segsum(y_s)) + y_s   (all bf16)
  ushort* bufs[3] = {ybA, ybB, ybC};
  ushort* ybin = ybA;
  for (int s = 0; s < 3; ++s) {
    ushort* ybout = bufs[(s + 1) % 3];
    agg_kernel<<<(NN / 4 * 64) / 256, 256, 0, stream>>>(ybin, row_start, adj, aggb);
    mlp_big<true, true><<<nblk, 1024, 0, stream>>>(
        aggb, gW1f, gb1, gW2f, gb2, ybin, ybout, NN);
    ybin = ybout;
  }

  // u1 = k1(y), u2 = k2(y), node_out = h(y) — one merged launch, 588 blocks
  mlp_tail3<<<dim3(nblk, 3), 1024, 0, stream>>>(
      ybin, k1W1f, k1b1, k1W2f, k1b2, k2W1f, k2b1, k2W2f, k2b2,
      hW1f, hb1, hW2f, hb2, u1b, u2b, (float*)d_out, NN);

  // edge_out = l(k(xe) + u1[src] + u2[dst])  — persistent, 256 blocks
  float* edge_out = (float*)d_out + (size_t)NN * 64;
  edge_kernel<<<256, 1024, 0, stream>>>(xe, esrc, edst, u1b, u2b, kW1f, kb1, kW2f, kb2,
                                        lW1f, lb1, lW2f, lb2, edge_out);
}

// Round 14
// 435.271 us; speedup vs baseline: 1.4129x; 1.2560x over previous
//
#include <hip/hip_runtime.h>
#include <hip/hip_bf16.h>

namespace {

constexpr int NN = 50000;
constexpr int NE = 800000;

typedef __attribute__((ext_vector_type(8))) short bf16x8;
typedef __attribute__((ext_vector_type(4))) float f32x4;

__device__ __forceinline__ short f2bf(float f) {
  union { __hip_bfloat16 h; short s; } u;
  u.h = __float2bfloat16(f);
  return u.s;
}
__device__ __forceinline__ float bf2f(short s) {
  union { unsigned int u; float f; } v;
  v.u = ((unsigned int)(unsigned short)s) << 16;
  return v.f;
}
__device__ __forceinline__ unsigned int pkbf2(float a, float b) {
  return (unsigned int)(unsigned short)f2bf(a) |
         ((unsigned int)(unsigned short)f2bf(b) << 16);
}

// ---------- weight repack (all 14 in one launch) ----------
struct WTab {
  const float* W[14];
  short* out[14];
  int din[14];
  int dout[14];
};

__global__ __launch_bounds__(256) void wfrag_all(WTab tab) {
  int wi = blockIdx.y;
  int din = tab.din[wi], dout = tab.dout[wi];
  int total = din * dout;
  int gid = blockIdx.x * 256 + threadIdx.x;
  if (gid >= total) return;
  const float* W = tab.W[wi];
  short* Wf = tab.out[wi];
  int j = gid & 7;
  int l = (gid >> 3) & 63;
  int rest = gid >> 9;
  int nK = din >> 5;
  int kc = rest % nK;
  int t = rest / nK;
  int n = t * 16 + (l & 15);
  int k = kc * 32 + (l >> 4) * 8 + j;
  Wf[gid] = f2bf(W[(size_t)k * dout + n]);
}

// ---------- CSR build ----------
__global__ __launch_bounds__(256) void hist_kernel(const int* __restrict__ edst,
                                                   int* __restrict__ deg) {
  int e = blockIdx.x * 256 + threadIdx.x;
  if (e < NE) atomicAdd(&deg[edst[e]], 1);
}

__global__ __launch_bounds__(256) void scan1_kernel(const int* __restrict__ deg,
                                                    int* __restrict__ excl,
                                                    int* __restrict__ bsum, int N) {
  __shared__ int s[256];
  int tid = threadIdx.x;
  int i = blockIdx.x * 256 + tid;
  int v = (i < N) ? deg[i] : 0;
  s[tid] = v;
  __syncthreads();
  for (int d = 1; d < 256; d <<= 1) {
    int t = (tid >= d) ? s[tid - d] : 0;
    __syncthreads();
    s[tid] += t;
    __syncthreads();
  }
  if (i < N) excl[i] = s[tid] - v;
  if (tid == 255) bsum[blockIdx.x] = s[255];
}

__global__ __launch_bounds__(256) void scan2_kernel(const int* __restrict__ bsum,
                                                    int* __restrict__ boff, int nb) {
  __shared__ int s[256];
  int tid = threadIdx.x;
  int v = (tid < nb) ? bsum[tid] : 0;
  s[tid] = v;
  __syncthreads();
  for (int d = 1; d < 256; d <<= 1) {
    int t = (tid >= d) ? s[tid - d] : 0;
    __syncthreads();
    s[tid] += t;
    __syncthreads();
  }
  if (tid <= nb) boff[tid] = s[tid] - v;
}

__global__ __launch_bounds__(256) void scan3_kernel(const int* __restrict__ excl,
                                                    const int* __restrict__ boff,
                                                    int* __restrict__ row_start,
                                                    int N, int nb) {
  int i = blockIdx.x * 256 + threadIdx.x;
  if (i < N) row_start[i] = excl[i] + boff[i >> 8];
  else if (i == N) row_start[N] = boff[nb];
}

__global__ __launch_bounds__(256) void fill_kernel(const int* __restrict__ esrc,
                                                   const int* __restrict__ edst,
                                                   const int* __restrict__ row_start,
                                                   int* __restrict__ cursor,
                                                   int* __restrict__ adj) {
  int e = blockIdx.x * 256 + threadIdx.x;
  if (e >= NE) return;
  int d = edst[e];
  int p = atomicAdd(&cursor[d], 1);
  adj[row_start[d] + p] = esrc[e];
}

// ---------- segment-sum: 4 nodes/wave, 16 lanes per node ----------
__global__ __launch_bounds__(256) void agg_kernel(const ushort* __restrict__ yb,
                                                  const int* __restrict__ row_start,
                                                  const int* __restrict__ adj,
                                                  ushort* __restrict__ aggb) {
  int gid = blockIdx.x * 256 + threadIdx.x;
  int lane = gid & 63;
  int g = lane >> 4;
  int q = lane & 15;
  int n = (gid >> 6) * 4 + g;
  int s0 = row_start[n], s1 = row_start[n + 1];
  float a0 = 0, a1 = 0, a2 = 0, a3 = 0, a4 = 0, a5 = 0, a6 = 0, a7 = 0;
  for (int base = s0; base < s1; base += 16) {
    int idx = 0;
    if (base + q < s1) idx = adj[base + q];
    int cnt = s1 - base;
    if (cnt > 16) cnt = 16;
#pragma unroll
    for (int j = 0; j < 16; ++j) {
      if (j < cnt) {
        int s = __shfl(idx, g * 16 + j);
        uint4 v = *reinterpret_cast<const uint4*>(yb + (size_t)s * 128 + q * 8);
        a0 += bf2f((short)(v.x & 0xffff)); a1 += bf2f((short)(v.x >> 16));
        a2 += bf2f((short)(v.y & 0xffff)); a3 += bf2f((short)(v.y >> 16));
        a4 += bf2f((short)(v.z & 0xffff)); a5 += bf2f((short)(v.z >> 16));
        a6 += bf2f((short)(v.w & 0xffff)); a7 += bf2f((short)(v.w >> 16));
      }
    }
  }
  uint4 o;
  o.x = pkbf2(a0, a1);
  o.y = pkbf2(a2, a3);
  o.z = pkbf2(a4, a5);
  o.w = pkbf2(a6, a7);
  *reinterpret_cast<uint4*>(aggb + (size_t)n * 128 + q * 8) = o;
}

// ---------- MFMA helpers ----------
// A tile: [rows][128 bf16 cols], row stride 256B, XOR swizzle ((row&7)<<4).
// B weights LDS layout == global fragment layout: granule (t*NKC+kc)*64+lane.

template <int NG, int NTHR>
__device__ __forceinline__ void wcopy(short* dst, const short* __restrict__ src,
                                      int tid) {
#pragma unroll
  for (int g0 = 0; g0 < NG; g0 += NTHR) {
    int g = g0 + tid;
    if (g < NG)
      *reinterpret_cast<bf16x8*>(dst + (size_t)g * 8) =
          *reinterpret_cast<const bf16x8*>(src + (size_t)g * 8);
  }
}

// NM=1 GEMM: one 16-row m-tile per wave, B from LDS.
// NOTE: no s_setprio here — measured (r7 vs r13): setprio around the MFMA
// cluster extends liveness past the 64-VGPR cap and costs ~160MB of spill
// round-trip (+92 µs) in the edge kernel.
template <int KCPH, int NT>
__device__ __forceinline__ void gemm16(const char* tb, const short* wbuf,
                                       int rbase, int lane, f32x4 (&acc)[NT]) {
#pragma unroll
  for (int kc = 0; kc < KCPH; ++kc) {
    int row = rbase + (lane & 15);
    int off = (row * 256 + kc * 64 + (lane >> 4) * 16) ^ ((row & 7) << 4);
    bf16x8 a = *reinterpret_cast<const bf16x8*>(tb + off);
#pragma unroll
    for (int t = 0; t < NT; ++t) {
      bf16x8 b = *reinterpret_cast<const bf16x8*>(wbuf + ((size_t)((t * KCPH + kc) * 64 + lane)) * 8);
      acc[t] = __builtin_amdgcn_mfma_f32_16x16x32_bf16(a, b, acc[t], 0, 0, 0);
    }
  }
}

template <int NT>
__device__ __forceinline__ void zero16(f32x4 (&acc)[NT]) {
  const f32x4 vzero = {0.f, 0.f, 0.f, 0.f};
#pragma unroll
  for (int t = 0; t < NT; ++t) acc[t] = vzero;
}

// epilogue for 16-row wave tile; bias pointer may be global or LDS
template <int NT, bool RELU>
__device__ __forceinline__ void epi16(char* dst, int rbase, int lane,
                                      const float* bias, f32x4 (&acc)[NT]) {
#pragma unroll
  for (int t = 0; t < NT; ++t) {
    int col = t * 16 + (lane & 15);
    float bb = bias[col];
#pragma unroll
    for (int i = 0; i < 4; ++i) {
      int row = rbase + (lane >> 4) * 4 + i;
      float h = acc[t][i] + bb;
      if (RELU) h = fmaxf(h, 0.f);
      int off = (row * 256 + col * 2) ^ ((row & 7) << 4);
      *reinterpret_cast<short*>(dst + off) = f2bf(h);
    }
  }
}

// ---------- node MLP f/g: 1024 thr, 16 waves x 16 rows, weights LDS-resident ----------
// SKIP: bf16 residual add from skipb (no f32 y buffer).
template <bool INBF16, bool SKIP>
__global__ __launch_bounds__(1024, 1) void mlp_big(
    const void* __restrict__ Xv,
    const short* __restrict__ W1f, const float* __restrict__ b1,
    const short* __restrict__ W2f, const float* __restrict__ b2,
    const ushort* __restrict__ skipb, ushort* __restrict__ bfout, int nrows) {
  __shared__ alignas(16) short tile_[256 * 128];  // 64 KB
  __shared__ alignas(16) short wb1[16384];        // 32 KB
  __shared__ alignas(16) short wb2[16384];        // 32 KB
  char* tb = reinterpret_cast<char*>(tile_);
  const int tid = threadIdx.x;
  const int lane = tid & 63;
  const int wave = tid >> 6;  // 0..15
  const int row0 = blockIdx.x * 256;
  const int wbase = wave * 16;

  wcopy<2048, 1024>(wb1, W1f, tid);
  wcopy<2048, 1024>(wb2, W2f, tid);
  __syncthreads();  // the only block barrier

  if constexpr (INBF16) {
    const ushort* X = (const ushort*)Xv;
#pragma unroll
    for (int it = 0; it < 4; ++it) {
      int idx = it * 64 + lane;
      int r = wbase + (idx >> 4);
      int c = idx & 15;
      int gr = row0 + r;
      bf16x8 v = {};
      if (gr < nrows) v = *reinterpret_cast<const bf16x8*>(X + (size_t)gr * 128 + c * 8);
      int off = (r * 256 + c * 16) ^ ((r & 7) << 4);
      *reinterpret_cast<bf16x8*>(tb + off) = v;
    }
  } else {
    const float* X = (const float*)Xv;
#pragma unroll
    for (int it = 0; it < 8; ++it) {
      int idx = it * 64 + lane;
      int r = wbase + (idx >> 5);
      int c = idx & 31;
      int gr = row0 + r;
      float4 v = make_float4(0.f, 0.f, 0.f, 0.f);
      if (gr < nrows) v = *reinterpret_cast<const float4*>(X + (size_t)gr * 128 + c * 4);
      short4 p;
      p.x = f2bf(v.x); p.y = f2bf(v.y); p.z = f2bf(v.z); p.w = f2bf(v.w);
      int off = (r * 256 + c * 8) ^ ((r & 7) << 4);
      *reinterpret_cast<short4*>(tb + off) = p;
    }
  }

  // GEMM1 (K=128) -> relu -> in place
  f32x4 acc[8];
  zero16(acc);
  gemm16<4, 8>(tb, wb1, wbase, lane, acc);
  epi16<8, true>(tb, wbase, lane, b1, acc);

  // GEMM2
  f32x4 acc2[8];
  zero16(acc2);
  gemm16<4, 8>(tb, wb2, wbase, lane, acc2);

#pragma unroll
  for (int t = 0; t < 8; ++t) {
    int col = t * 16 + (lane & 15);
    float bb = b2[col];
#pragma unroll
    for (int i = 0; i < 4; ++i) {
      int row = wbase + (lane >> 4) * 4 + i;
      int gr = row0 + row;
      if (gr < nrows) {
        float v = acc2[t][i] + bb;
        if constexpr (SKIP)
          v += bf2f((short)skipb[(size_t)gr * 128 + col]);
        int off = (row * 256 + col * 2) ^ ((row & 7) << 4);
        *reinterpret_cast<short*>(tb + off) = f2bf(v);
      }
    }
  }
  // coalesced bf16 store of this wave's 16 rows
#pragma unroll
  for (int rr = 0; rr < 16; ++rr) {
    int row = wbase + rr;
    int gr = row0 + row;
    if (gr < nrows) {
      int off = (row * 256 + lane * 4) ^ ((row & 7) << 4);
      unsigned int v = *reinterpret_cast<const unsigned int*>(tb + off);
      *reinterpret_cast<unsigned int*>(bfout + (size_t)gr * 128 + lane * 2) = v;
    }
  }
}

// ---------- merged tail: gridDim.y selects k1 / k2 / h ----------
__global__ __launch_bounds__(1024, 1) void mlp_tail3(
    const ushort* __restrict__ X,
    const short* __restrict__ k1W1f, const float* __restrict__ k1b1,
    const short* __restrict__ k1W2f, const float* __restrict__ k1b2,
    const short* __restrict__ k2W1f, const float* __restrict__ k2b1,
    const short* __restrict__ k2W2f, const float* __restrict__ k2b2,
    const short* __restrict__ hW1f, const float* __restrict__ hb1,
    const short* __restrict__ hW2f, const float* __restrict__ hb2,
    ushort* __restrict__ u1b, ushort* __restrict__ u2b,
    float* __restrict__ node_out, int nrows) {
  __shared__ alignas(16) short tile_[256 * 128];  // 64 KB
  __shared__ alignas(16) short wb1[16384];        // 32 KB
  __shared__ alignas(16) short wb2[16384];        // 32 KB
  char* tb = reinterpret_cast<char*>(tile_);
  const int tid = threadIdx.x;
  const int lane = tid & 63;
  const int wave = tid >> 6;
  const int row0 = blockIdx.x * 256;
  const int wbase = wave * 16;
  const int mode = blockIdx.y;  // 0: k1->u1b, 1: k2->u2b, 2: h->node_out

  const short* W1f = (mode == 0) ? k1W1f : (mode == 1) ? k2W1f : hW1f;
  const float* b1 = (mode == 0) ? k1b1 : (mode == 1) ? k2b1 : hb1;
  const short* W2f = (mode == 0) ? k1W2f : (mode == 1) ? k2W2f : hW2f;
  const float* b2 = (mode == 0) ? k1b2 : (mode == 1) ? k2b2 : hb2;

  wcopy<2048, 1024>(wb1, W1f, tid);
  if (mode < 2) wcopy<2048, 1024>(wb2, W2f, tid);
  else wcopy<1024, 1024>(wb2, W2f, tid);
  __syncthreads();  // the only block barrier

#pragma unroll
  for (int it = 0; it < 4; ++it) {
    int idx = it * 64 + lane;
    int r = wbase + (idx >> 4);
    int c = idx & 15;
    int gr = row0 + r;
    bf16x8 v = {};
    if (gr < nrows) v = *reinterpret_cast<const bf16x8*>(X + (size_t)gr * 128 + c * 8);
    int off = (r * 256 + c * 16) ^ ((r & 7) << 4);
    *reinterpret_cast<bf16x8*>(tb + off) = v;
  }

  f32x4 acc[8];
  zero16(acc);
  gemm16<4, 8>(tb, wb1, wbase, lane, acc);
  epi16<8, true>(tb, wbase, lane, b1, acc);

  if (mode < 2) {
    f32x4 acc2[8];
    zero16(acc2);
    gemm16<4, 8>(tb, wb2, wbase, lane, acc2);
    epi16<8, false>(tb, wbase, lane, b2, acc2);
    ushort* ub = (mode == 0) ? u1b : u2b;
#pragma unroll
    for (int rr = 0; rr < 16; ++rr) {
      int row = wbase + rr;
      int gr = row0 + row;
      if (gr < nrows) {
        int off = (row * 256 + lane * 4) ^ ((row & 7) << 4);
        unsigned int v = *reinterpret_cast<const unsigned int*>(tb + off);
        *reinterpret_cast<unsigned int*>(ub + (size_t)gr * 128 + lane * 2) = v;
      }
    }
  } else {
    f32x4 acc2[4];
    zero16(acc2);
    gemm16<4, 4>(tb, wb2, wbase, lane, acc2);
#pragma unroll
    for (int t = 0; t < 4; ++t) {
      int col = t * 16 + (lane & 15);
      float bb = b2[col];
#pragma unroll
      for (int i = 0; i < 4; ++i) {
        int row = wbase + (lane >> 4) * 4 + i;
        int gr = row0 + row;
        if (gr < nrows) node_out[(size_t)gr * 64 + col] = acc2[t][i] + bb;
      }
    }
  }
}

// ---------- edge kernel: persistent, 1024 thr, 16 waves x 16 edges (r7 exact) ----------
__device__ __forceinline__ void load_tile_regs(const float* __restrict__ xe,
                                               const int* __restrict__ esrc,
                                               const int* __restrict__ edst,
                                               int ebase, int lane,
                                               int& vint, float4 (&xr)[4]) {
  vint = (lane < 32) ? esrc[ebase + (lane & 15)] : edst[ebase + (lane & 15)];
#pragma unroll
  for (int i = 0; i < 4; ++i) {
    int idx = i * 64 + lane;
    int r = idx >> 4, c = idx & 15;
    xr[i] = *reinterpret_cast<const float4*>(xe + (size_t)(ebase + r) * 64 + c * 4);
  }
}

__global__ __launch_bounds__(1024, 1) void edge_kernel(
    const float* __restrict__ xe, const int* __restrict__ esrc,
    const int* __restrict__ edst, const ushort* __restrict__ u1b,
    const ushort* __restrict__ u2b,
    const short* __restrict__ kW1f, const float* __restrict__ kb1,
    const short* __restrict__ kW2f, const float* __restrict__ kb2,
    const short* __restrict__ lW1f, const float* __restrict__ lb1,
    const short* __restrict__ lW2f, const float* __restrict__ lb2,
    float* __restrict__ out) {
  __shared__ alignas(16) short wK1[8192];        // 16 KB (K=64, N=128)
  __shared__ alignas(16) short wK2[16384];       // 32 KB
  __shared__ alignas(16) short wL1[16384];       // 32 KB
  __shared__ alignas(16) short wL2[4096];        // 8 KB  (K=128, N=32)
  __shared__ alignas(16) short tile_[256 * 128]; // 64 KB
  __shared__ float biasL[416];                   // kb1|kb2|lb1|lb2
  char* tb = reinterpret_cast<char*>(tile_);
  const int tid = threadIdx.x;
  const int lane = tid & 63;
  const int wave = tid >> 6;  // 0..15
  const int f4 = lane & 31;
  const int hs = lane >> 5;
  const int wbase = wave * 16;

  wcopy<1024, 1024>(wK1, kW1f, tid);
  wcopy<2048, 1024>(wK2, kW2f, tid);
  wcopy<2048, 1024>(wL1, lW1f, tid);
  wcopy<512, 1024>(wL2, lW2f, tid);
  if (tid < 128) biasL[tid] = kb1[tid];
  else if (tid < 256) biasL[tid] = kb2[tid - 128];
  else if (tid < 384) biasL[tid] = lb1[tid - 256];
  else if (tid < 416) biasL[tid] = lb2[tid - 384];
  __syncthreads();  // the only block barrier

  constexpr int NTILES = NE / 256;  // 3125
  int tile = blockIdx.x;
  int vnext;
  float4 xr[4];
  load_tile_regs(xe, esrc, edst, tile * 256 + wbase, lane, vnext, xr);

  for (; tile < NTILES; tile += gridDim.x) {
    const int ebase = tile * 256 + wbase;
    const int vcur = vnext;

    // write prefetched xe (bf16) into my 16 rows, cols 0..63
#pragma unroll
    for (int i = 0; i < 4; ++i) {
      int idx = i * 64 + lane;
      int r = idx >> 4, c = idx & 15;
      short4 p;
      p.x = f2bf(xr[i].x); p.y = f2bf(xr[i].y);
      p.z = f2bf(xr[i].z); p.w = f2bf(xr[i].w);
      int rr = wbase + r;
      int off = (rr * 256 + c * 8) ^ ((rr & 7) << 4);
      *reinterpret_cast<short4*>(tb + off) = p;
    }

    // gather chunk A (local rows i*2+hs, i<4)
    ushort4 ga[4], gb[4];
#pragma unroll
    for (int i = 0; i < 4; ++i) {
      int s = __shfl(vcur, i * 2 + hs);
      int d = __shfl(vcur, 32 + i * 2 + hs);
      ga[i] = *reinterpret_cast<const ushort4*>(u1b + (size_t)s * 128 + f4 * 4);
      gb[i] = *reinterpret_cast<const ushort4*>(u2b + (size_t)d * 128 + f4 * 4);
    }

    // k GEMM1 (K=64)
    f32x4 acc[8];
    zero16(acc);
    gemm16<2, 8>(tb, wK1, wbase, lane, acc);
    epi16<8, true>(tb, wbase, lane, &biasL[0], acc);

    // issue chunk B; combine chunk A
    ushort4 ga2[4], gb2[4];
#pragma unroll
    for (int i = 0; i < 4; ++i) {
      int s = __shfl(vcur, (4 + i) * 2 + hs);
      int d = __shfl(vcur, 32 + (4 + i) * 2 + hs);
      ga2[i] = *reinterpret_cast<const ushort4*>(u1b + (size_t)s * 128 + f4 * 4);
      gb2[i] = *reinterpret_cast<const ushort4*>(u2b + (size_t)d * 128 + f4 * 4);
    }
    uint2 gsum[8];
#pragma unroll
    for (int i = 0; i < 4; ++i) {
      float s0 = bf2f((short)ga[i].x) + bf2f((short)gb[i].x);
      float s1 = bf2f((short)ga[i].y) + bf2f((short)gb[i].y);
      float s2 = bf2f((short)ga[i].z) + bf2f((short)gb[i].z);
      float s3 = bf2f((short)ga[i].w) + bf2f((short)gb[i].w);
      gsum[i] = make_uint2(pkbf2(s0, s1), pkbf2(s2, s3));
    }

    // k GEMM2 (K=128)
    zero16(acc);
    gemm16<4, 8>(tb, wK2, wbase, lane, acc);
    epi16<8, false>(tb, wbase, lane, &biasL[128], acc);

#pragma unroll
    for (int i = 0; i < 4; ++i) {
      float s0 = bf2f((short)ga2[i].x) + bf2f((short)gb2[i].x);
      float s1 = bf2f((short)ga2[i].y) + bf2f((short)gb2[i].y);
      float s2 = bf2f((short)ga2[i].z) + bf2f((short)gb2[i].z);
      float s3 = bf2f((short)ga2[i].w) + bf2f((short)gb2[i].w);
      gsum[4 + i] = make_uint2(pkbf2(s0, s1), pkbf2(s2, s3));
    }

    // e_hid += u1[src] + u2[dst]  (wave-private rows)
#pragma unroll
    for (int i = 0; i < 8; ++i) {
      int r = wbase + i * 2 + hs;
      int off = (r * 256 + f4 * 8) ^ ((r & 7) << 4);
      short4 c = *reinterpret_cast<short4*>(tb + off);
      uint2 g = gsum[i];
      short4 nw;
      nw.x = f2bf(bf2f(c.x) + bf2f((short)(g.x & 0xffff)));
      nw.y = f2bf(bf2f(c.y) + bf2f((short)(g.x >> 16)));
      nw.z = f2bf(bf2f(c.z) + bf2f((short)(g.y & 0xffff)));
      nw.w = f2bf(bf2f(c.w) + bf2f((short)(g.y >> 16)));
      *reinterpret_cast<short4*>(tb + off) = nw;
    }

    // prefetch next tile's xe + endpoints (hides under GEMM3/4)
    int nt2 = tile + gridDim.x;
    if (nt2 < NTILES)
      load_tile_regs(xe, esrc, edst, nt2 * 256 + wbase, lane, vnext, xr);

    // l GEMM3 (K=128)
    zero16(acc);
    gemm16<4, 8>(tb, wL1, wbase, lane, acc);
    epi16<8, true>(tb, wbase, lane, &biasL[256], acc);

    // l GEMM4 (K=128, N=32)
    f32x4 acc4[2];
    zero16(acc4);
    gemm16<4, 2>(tb, wL2, wbase, lane, acc4);

    // direct output stores (r7 layout — best measured)
#pragma unroll
    for (int t = 0; t < 2; ++t) {
      int col = t * 16 + (lane & 15);
      float bb = biasL[384 + col];
#pragma unroll
      for (int i = 0; i < 4; ++i) {
        int row = (lane >> 4) * 4 + i;
        out[(size_t)(ebase + row) * 32 + col] = acc4[t][i] + bb;
      }
    }
  }
}

}  // namespace

extern "C" void kernel_launch(void* const* d_in, const int* in_sizes, int n_in,
                              void* d_out, int out_size, void* d_ws, size_t ws_size,
                              hipStream_t stream) {
  const float* x = (const float*)d_in[0];
  const float* xe = (const float*)d_in[1];
  const int* eidx = (const int*)d_in[2];
  const int* esrc = eidx;
  const int* edst = eidx + NE;

  const float* fb1 = (const float*)d_in[4];
  const float* fb2 = (const float*)d_in[6];
  const float* gb1 = (const float*)d_in[8];
  const float* gb2 = (const float*)d_in[10];
  const float* hb1 = (const float*)d_in[12];
  const float* hb2 = (const float*)d_in[14];
  const float* k1b1 = (const float*)d_in[16];
  const float* k1b2 = (const float*)d_in[18];
  const float* k2b1 = (const float*)d_in[20];
  const float* k2b2 = (const float*)d_in[22];
  const float* kb1 = (const float*)d_in[24];
  const float* kb2 = (const float*)d_in[26];
  const float* lb1 = (const float*)d_in[28];
  const float* lb2 = (const float*)d_in[30];

  char* ws = (char*)d_ws;
  size_t off = 0;
  auto alloc = [&](size_t bytes) -> void* {
    void* p = ws + off;
    off = (off + bytes + 255) & ~(size_t)255;
    return p;
  };
  ushort* ybA = (ushort*)alloc((size_t)NN * 128 * 2);
  ushort* ybB = (ushort*)alloc((size_t)NN * 128 * 2);
  ushort* ybC = (ushort*)alloc((size_t)NN * 128 * 2);
  ushort* aggb = (ushort*)alloc((size_t)NN * 128 * 2);
  ushort* u1b = (ushort*)alloc((size_t)NN * 128 * 2);
  ushort* u2b = (ushort*)alloc((size_t)NN * 128 * 2);
  int* deg = (int*)alloc((size_t)NN * 4);
  int* excl = (int*)alloc((size_t)NN * 4);
  int* bsum = (int*)alloc(256 * 4);
  int* boff = (int*)alloc(256 * 4);
  int* row_start = (int*)alloc((size_t)(NN + 16) * 4);
  int* cursor = (int*)alloc((size_t)NN * 4);
  int* adj = (int*)alloc((size_t)NE * 4);

  // weight fragment buffers (single fused repack launch)
  const int wi[14] = {3, 5, 7, 9, 11, 13, 15, 17, 19, 21, 23, 25, 27, 29};
  const int wdin[14] = {128, 128, 128, 128, 128, 128, 128, 128, 128, 128, 64, 128, 128, 128};
  const int wdout[14] = {128, 128, 128, 128, 128, 64, 128, 128, 128, 128, 128, 128, 128, 32};
  WTab tab;
  short* wf[14];
  for (int i = 0; i < 14; ++i) {
    size_t elems = (size_t)wdin[i] * wdout[i];
    wf[i] = (short*)alloc(elems * 2);
    tab.W[i] = (const float*)d_in[wi[i]];
    tab.out[i] = wf[i];
    tab.din[i] = wdin[i];
    tab.dout[i] = wdout[i];
  }
  wfrag_all<<<dim3(64, 14, 1), 256, 0, stream>>>(tab);

  short* fW1f = wf[0];  short* fW2f = wf[1];
  short* gW1f = wf[2];  short* gW2f = wf[3];
  short* hW1f = wf[4];  short* hW2f = wf[5];
  short* k1W1f = wf[6]; short* k1W2f = wf[7];
  short* k2W1f = wf[8]; short* k2W2f = wf[9];
  short* kW1f = wf[10]; short* kW2f = wf[11];
  short* lW1f = wf[12]; short* lW2f = wf[13];

  // CSR build
  const int nb = (NN + 255) / 256;  // 196
  hipMemsetAsync(deg, 0, (size_t)NN * 4, stream);
  hist_kernel<<<(NE + 255) / 256, 256, 0, stream>>>(edst, deg);
  scan1_kernel<<<nb, 256, 0, stream>>>(deg, excl, bsum, NN);
  scan2_kernel<<<1, 256, 0, stream>>>(bsum, boff, nb);
  scan3_kernel<<<(NN + 256) / 256 + 1, 256, 0, stream>>>(excl, boff, row_start, NN, nb);
  hipMemsetAsync(cursor, 0, (size_t)NN * 4, stream);
  fill_kernel<<<(NE + 255) / 256, 256, 0, stream>>>(esrc, edst, row_start, cursor, adj);

  const int nblk = (NN + 255) / 256;  // 196 tiles of 256 rows

  // y0 = f(x)  (bf16 only — skip chain carried in bf16)
  mlp_big<false, false><<<nblk, 1024, 0, stream>>>(
      x, fW1f, fb1, fW2f, fb2, nullptr, ybA, NN);

  // 3 MP steps: y_{s+1} = g(segsum(y_s)) + y_s   (all bf16)
  ushort* bufs[3] = {ybA, ybB, ybC};
  ushort* ybin = ybA;
  for (int s = 0; s < 3; ++s) {
    ushort* ybout = bufs[(s + 1) % 3];
    agg_kernel<<<(NN / 4 * 64) / 256, 256, 0, stream>>>(ybin, row_start, adj, aggb);
    mlp_big<true, true><<<nblk, 1024, 0, stream>>>(
        aggb, gW1f, gb1, gW2f, gb2, ybin, ybout, NN);
    ybin = ybout;
  }

  // u1 = k1(y), u2 = k2(y), node_out = h(y) — one merged launch, 588 blocks
  mlp_tail3<<<dim3(nblk, 3), 1024, 0, stream>>>(
      ybin, k1W1f, k1b1, k1W2f, k1b2, k2W1f, k2b1, k2W2f, k2b2,
      hW1f, hb1, hW2f, hb2, u1b, u2b, (float*)d_out, NN);

  // edge_out = l(k(xe) + u1[src] + u2[dst])  — persistent, 256 blocks
  float* edge_out = (float*)d_out + (size_t)NN * 64;
  edge_kernel<<<256, 1024, 0, stream>>>(xe, esrc, edst, u1b, u2b, kW1f, kb1, kW2f, kb2,
                                        lW1f, lb1, lW2f, lb2, edge_out);
}